// Round 10
// baseline (461.228 us; speedup 1.0000x reference)
//
#include <hip/hip_runtime.h>
#include <hip/hip_fp16.h>
#include <math.h>

#define THREADS 256
#define KC 32
#define BSHIFT 9          // 512 nodes per bucket
#define BNODES (1 << BSHIFT)
#define NB_MAX 256        // max buckets (N<=131072)
#define ECHUNK 4096       // edges per block in binning kernels

__device__ __forceinline__ float clipf(float v){ return fminf(fmaxf(v, -10.f), 10.f); }

typedef __attribute__((ext_vector_type(8))) short bf16x8;
typedef __attribute__((ext_vector_type(4))) float f32x4;
typedef __attribute__((ext_vector_type(16))) float f32x16;

// split fp32 into bf16 hi + bf16 lo (3-term split-GEMM decomposition)
__device__ __forceinline__ void split_bf16(float f, short& hi, short& lo){
    union { float f; unsigned u; } a; a.f = f;
    unsigned r = (a.u + 0x7FFFu + ((a.u >> 16) & 1u)) & 0xFFFF0000u;
    hi = (short)(r >> 16);
    union { unsigned u; float f; } b; b.u = r;
    float rem = f - b.f;
    union { float f; unsigned u; } c; c.f = rem;
    unsigned r2 = c.u + 0x7FFFu + ((c.u >> 16) & 1u);
    lo = (short)(r2 >> 16);
}

// ---------------------------------------------------------------- fused setup:
// [0,nConv)            x -> fp16
// [nConv,+nPrep)       weight prep (split-bf16 + transposes + bias tables)
// [+nFlag)             flag users
// [rest]               bucket histogram
__global__ __launch_bounds__(256) void setup_k(
        const float* __restrict__ x, __half* __restrict__ xh, long n8, int nConv,
        const float* __restrict__ w_l0, const float* __restrict__ w_r0,
        const float* __restrict__ w_l1, const float* __restrict__ w_r1,
        const float* __restrict__ wc0,  const float* __restrict__ wc1,
        const float* __restrict__ w_ih, const float* __restrict__ b_ih, const float* __restrict__ b_hh,
        short* __restrict__ wt0h, short* __restrict__ wt0l,
        short* __restrict__ wt1h, short* __restrict__ wt1l,
        short* __restrict__ wgh,  short* __restrict__ wgl,
        short* __restrict__ wc0h, short* __restrict__ wc0l,
        float* __restrict__ wtc1, float* __restrict__ bsum, float* __restrict__ ohtab, int nPrep,
        const int* __restrict__ uid, int B, int* __restrict__ flag, int nFlag,
        const int* __restrict__ dstv, int E, int nbuckets, int* __restrict__ bcnt){
    __shared__ int hsh[NB_MAX];
    int b = blockIdx.x;
    if (b < nConv){
        long t = (long)b*256 + threadIdx.x;
        if (t >= n8) return;
        long i = t*8;
        float4 a = *(const float4*)(x + i);
        float4 bb = *(const float4*)(x + i + 4);
        union { __half2 h[4]; float4 f; } u;
        u.h[0] = __floats2half2_rn(a.x, a.y);
        u.h[1] = __floats2half2_rn(a.z, a.w);
        u.h[2] = __floats2half2_rn(bb.x, bb.y);
        u.h[3] = __floats2half2_rn(bb.z, bb.w);
        *(float4*)(xh + i) = u.f;
    } else if (b < nConv + nPrep){
        int idx = (b - nConv)*256 + threadIdx.x;
        if (idx < 32768){
            int n = idx >> 8, k = idx & 255;
            float f = (k < 128) ? w_l0[n*128 + k] : w_r0[n*128 + (k - 128)];
            short h, l; split_bf16(f, h, l);
            wt0h[idx] = h; wt0l[idx] = l;
        } else if (idx < 65536){
            int i = idx - 32768;
            int n = i >> 8, k = i & 255;
            float f = (k < 128) ? w_l1[n*128 + k] : w_r1[n*128 + (k - 128)];
            short h, l; split_bf16(f, h, l);
            wt1h[i] = h; wt1l[i] = l;
        } else if (idx < 163840){
            int i = idx - 65536;
            int n = i >> 8, k = i & 255;       // n in [0,384)
            int j = n + ((n >= 128) ? 128 : 0);
            float f = w_ih[j*261 + k];
            short h, l; split_bf16(f, h, l);
            wgh[i] = h; wgl[i] = l;
        } else if (idx < 196608){
            int i = idx - 163840;
            float f = wc0[i];                  // [128][256] already [n][k]
            short h, l; split_bf16(f, h, l);
            wc0h[i] = h; wc0l[i] = l;
        } else if (idx < 204800){
            int i = idx - 196608;
            int j = i >> 7, k = i & 127;
            wtc1[k*64 + j] = wc1[j*128 + k];
        } else if (idx < 205184){
            int jj = idx - 204800;
            int j = jj + ((jj >= 128) ? 128 : 0);
            bsum[jj] = b_ih[j] + b_hh[j];
            for (int r = 0; r < 5; ++r) ohtab[r*384 + jj] = w_ih[j*261 + 256 + r];
        }
    } else if (b < nConv + nPrep + nFlag){
        int i = (b - nConv - nPrep)*256 + threadIdx.x;
        if (i < B) flag[uid[i]] = 1;
    } else {
        int lb = b - nConv - nPrep - nFlag;
        int b0 = lb * ECHUNK;
        int b1 = min(b0 + ECHUNK, E);
        for (int i = threadIdx.x; i < nbuckets; i += 256) hsh[i] = 0;
        __syncthreads();
        for (int i = b0 + threadIdx.x; i < b1; i += 256)
            atomicAdd(&hsh[dstv[i] >> BSHIFT], 1);
        __syncthreads();
        for (int i = threadIdx.x; i < nbuckets; i += 256){
            int c = hsh[i];
            if (c) atomicAdd(&bcnt[i], c);
        }
    }
}

// ---------------------------------------------------------------- CSR build (bucket-first)
__global__ __launch_bounds__(256) void scan_b(const int* __restrict__ bcnt, int nb, int E, int N,
                                              int* __restrict__ boffs, int* __restrict__ bcur, int* __restrict__ row_start){
    __shared__ int sh[256];
    int t = threadIdx.x;
    int v = (t < nb) ? bcnt[t] : 0;
    sh[t] = v; __syncthreads();
    for (int off = 1; off < 256; off <<= 1){
        int u = (t >= off) ? sh[t-off] : 0;
        __syncthreads();
        sh[t] += u;
        __syncthreads();
    }
    int ex = sh[t] - v;
    if (t < nb){ boffs[t] = ex; bcur[t] = ex; }
    if (t == 0){ boffs[nb] = E; row_start[N] = E; }
}

__global__ __launch_bounds__(256) void bin_edges_priv(const int* __restrict__ srcv, const int* __restrict__ dstv, int E,
                                                      int nbuckets, int* __restrict__ bcur, int2* __restrict__ pairs){
    __shared__ int cnt[NB_MAX];
    __shared__ int base[NB_MAX];
    int b0 = blockIdx.x * ECHUNK;
    int b1 = min(b0 + ECHUNK, E);
    for (int i = threadIdx.x; i < nbuckets; i += 256) cnt[i] = 0;
    __syncthreads();
    for (int i = b0 + threadIdx.x; i < b1; i += 256)
        atomicAdd(&cnt[dstv[i] >> BSHIFT], 1);
    __syncthreads();
    for (int i = threadIdx.x; i < nbuckets; i += 256){
        int c = cnt[i];
        base[i] = c ? atomicAdd(&bcur[i], c) : 0;
    }
    __syncthreads();
    for (int i = threadIdx.x; i < nbuckets; i += 256) cnt[i] = 0;
    __syncthreads();
    for (int i = b0 + threadIdx.x; i < b1; i += 256){
        int d = dstv[i];
        int bk = d >> BSHIFT;
        int loc = atomicAdd(&cnt[bk], 1);
        pairs[base[bk] + loc] = make_int2(d, srcv[i]);
    }
}

__global__ __launch_bounds__(256) void fill_bucket2(const int2* __restrict__ pairs, const int* __restrict__ boffs,
                                                    int* __restrict__ row_start, int* __restrict__ col_idx, int N){
    __shared__ int cur[BNODES];
    __shared__ int sh[256];
    int b  = blockIdx.x;
    int n0 = b << BSHIFT;
    int nn = min(BNODES, N - n0);
    int s = boffs[b], e = boffs[b+1];
    int t = threadIdx.x;
    cur[2*t]   = 0;
    cur[2*t+1] = 0;
    __syncthreads();
    for (int i = s + t; i < e; i += 256)
        atomicAdd(&cur[pairs[i].x - n0], 1);
    __syncthreads();
    int c0 = cur[2*t], c1 = cur[2*t+1];
    int s2 = c0 + c1;
    sh[t] = s2; __syncthreads();
    for (int off = 1; off < 256; off <<= 1){
        int u = (t >= off) ? sh[t-off] : 0;
        __syncthreads();
        sh[t] += u;
        __syncthreads();
    }
    int ex = sh[t] - s2;
    __syncthreads();
    cur[2*t]   = s + ex;
    cur[2*t+1] = s + ex + c0;
    __syncthreads();
    for (int i = t; i < nn; i += 256) row_start[n0 + i] = cur[i];
    __syncthreads();
    for (int i = s + t; i < e; i += 256){
        int2 p = pairs[i];
        int loc = atomicAdd(&cur[p.x - n0], 1);
        col_idx[loc] = p.y;
    }
}

__global__ __launch_bounds__(256) void compact_flags(const int* __restrict__ flag, int N, int* __restrict__ list, int* __restrict__ cnt){
    int i = blockIdx.x*256 + threadIdx.x;
    if (i < N && flag[i]){ int p = atomicAdd(cnt, 1); list[p] = i; }
}

// ---------------------------------------------------------------- fp16 mean aggregation (fp32 accum)
__device__ __forceinline__ void accumh(float4& a0, float4& a1, float4 v){
    const __half2* h = (const __half2*)&v;
    float2 f0 = __half22float2(h[0]);
    float2 f1 = __half22float2(h[1]);
    float2 f2 = __half22float2(h[2]);
    float2 f3 = __half22float2(h[3]);
    a0.x += f0.x; a0.y += f0.y; a0.z += f1.x; a0.w += f1.y;
    a1.x += f2.x; a1.y += f2.y; a1.z += f3.x; a1.w += f3.y;
}

// shared body: wave aggregates node's fp16 row-mean into fp32 out (4 edge-groups x 16 lanes)
__device__ __forceinline__ void agg_body(const __half* __restrict__ feat, const int* __restrict__ row_start,
                                         const int* __restrict__ col_idx, float* __restrict__ outmean,
                                         int node, int lane){
    int g  = lane >> 4;
    int sl = lane & 15;
    int s = row_start[node], e = row_start[node+1];
    const float4* f16 = (const float4*)feat;
    float4 a0 = make_float4(0.f,0.f,0.f,0.f);
    float4 a1 = make_float4(0.f,0.f,0.f,0.f);
    int i = s + g;
    for (; i + 12 < e; i += 16){       // 4 loads in flight
        int s0 = col_idx[i];
        int s1 = col_idx[i+4];
        int s2 = col_idx[i+8];
        int s3 = col_idx[i+12];
        float4 v0 = f16[(long)s0*16 + sl];
        float4 v1 = f16[(long)s1*16 + sl];
        float4 v2 = f16[(long)s2*16 + sl];
        float4 v3 = f16[(long)s3*16 + sl];
        accumh(a0, a1, v0);
        accumh(a0, a1, v1);
        accumh(a0, a1, v2);
        accumh(a0, a1, v3);
    }
    if (i + 4 < e){                    // 2-deep tail
        int s0 = col_idx[i];
        int s1 = col_idx[i+4];
        float4 v0 = f16[(long)s0*16 + sl];
        float4 v1 = f16[(long)s1*16 + sl];
        accumh(a0, a1, v0);
        accumh(a0, a1, v1);
        i += 8;
    }
    if (i < e){                        // final single
        float4 v0 = f16[(long)col_idx[i]*16 + sl];
        accumh(a0, a1, v0);
    }
    a0.x += __shfl_xor(a0.x, 16, 64); a0.x += __shfl_xor(a0.x, 32, 64);
    a0.y += __shfl_xor(a0.y, 16, 64); a0.y += __shfl_xor(a0.y, 32, 64);
    a0.z += __shfl_xor(a0.z, 16, 64); a0.z += __shfl_xor(a0.z, 32, 64);
    a0.w += __shfl_xor(a0.w, 16, 64); a0.w += __shfl_xor(a0.w, 32, 64);
    a1.x += __shfl_xor(a1.x, 16, 64); a1.x += __shfl_xor(a1.x, 32, 64);
    a1.y += __shfl_xor(a1.y, 16, 64); a1.y += __shfl_xor(a1.y, 32, 64);
    a1.z += __shfl_xor(a1.z, 16, 64); a1.z += __shfl_xor(a1.z, 32, 64);
    a1.w += __shfl_xor(a1.w, 16, 64); a1.w += __shfl_xor(a1.w, 32, 64);
    if (g == 0){
        float inv = 1.f / fmaxf((float)(e - s), 1.f);
        a0.x *= inv; a0.y *= inv; a0.z *= inv; a0.w *= inv;
        a1.x *= inv; a1.y *= inv; a1.z *= inv; a1.w *= inv;
        float4* om = (float4*)(outmean + (long)node*128 + sl*8);
        om[0] = a0;
        om[1] = a1;
    }
}

__global__ __launch_bounds__(256) void aggregate_h16(const __half* __restrict__ feat, const int* __restrict__ row_start,
                                                     const int* __restrict__ col_idx,
                                                     float* __restrict__ outmean, int N){
    int wave = (blockIdx.x*256 + threadIdx.x) >> 6;
    if (wave >= N) return;
    agg_body(feat, row_start, col_idx, outmean, wave, threadIdx.x & 63);
}

__global__ __launch_bounds__(256) void aggregate_kh(const __half* __restrict__ feat, const int* __restrict__ row_start,
                                                    const int* __restrict__ col_idx,
                                                    const int* __restrict__ list, const int* __restrict__ cnt,
                                                    float* __restrict__ outmean){
    int wave = (blockIdx.x*256 + threadIdx.x) >> 6;
    if (wave >= *cnt) return;
    agg_body(feat, row_start, col_idx, outmean, list[wave], threadIdx.x & 63);
}

// ---------------------------------------------------------------- layer-0 GEMM via split-bf16 32x32x16 MFMA
// h = relu([mean0|x] @ wt0^T + b_l0); also emits fp16 h for the layer-1 gather.
__global__ __launch_bounds__(256) void gemm32_mfma(const float* __restrict__ mean0, const float* __restrict__ x,
                                                   const short* __restrict__ wh, const short* __restrict__ wl,
                                                   const float* __restrict__ bias, float* __restrict__ out,
                                                   __half* __restrict__ outh, int M){
    __shared__ __align__(16) short Ah[8*64*8];   // 8 regions x 64 lanes x 8 shorts = 8 KB
    __shared__ __align__(16) short Al[8*64*8];
    __shared__ __align__(16) short Wh[8*64*8];
    __shared__ __align__(16) short Wl[8*64*8];

    const int tid  = threadIdx.x;
    const int row0 = blockIdx.x * 128;
    const int wave = tid >> 6, lane = tid & 63;
    const int wr = wave >> 1, wc = wave & 1;
    const int c32 = lane & 31, gg = lane >> 5;

    f32x16 acc[2][2];
    #pragma unroll
    for (int rm = 0; rm < 2; ++rm)
        #pragma unroll
        for (int cn = 0; cn < 2; ++cn)
            #pragma unroll
            for (int r = 0; r < 16; ++r) acc[rm][cn][r] = 0.f;

    for (int ko = 0; ko < 256; ko += KC){
        #pragma unroll
        for (int it = 0; it < 2; ++it){
            int cid = it*256 + tid;
            int row = cid >> 2, s = (cid >> 1) & 1, g = cid & 1;
            int grow = row0 + row; if (grow >= M) grow = M - 1;
            int k = ko + s*16 + g*8;
            const float* p = (k < 128) ? (mean0 + (long)grow*128 + k) : (x + (long)grow*128 + (k - 128));
            float4 va = *(const float4*)p;
            float4 vb = *(const float4*)(p + 4);
            union { short s8[8]; int4 v; } ph, pl;
            split_bf16(va.x, ph.s8[0], pl.s8[0]);
            split_bf16(va.y, ph.s8[1], pl.s8[1]);
            split_bf16(va.z, ph.s8[2], pl.s8[2]);
            split_bf16(va.w, ph.s8[3], pl.s8[3]);
            split_bf16(vb.x, ph.s8[4], pl.s8[4]);
            split_bf16(vb.y, ph.s8[5], pl.s8[5]);
            split_bf16(vb.z, ph.s8[6], pl.s8[6]);
            split_bf16(vb.w, ph.s8[7], pl.s8[7]);
            int slot = ((s*4 + (row >> 5))*64 + g*32 + (row & 31)) * 8;
            *(int4*)&Ah[slot] = ph.v;
            *(int4*)&Al[slot] = pl.v;
        }
        #pragma unroll
        for (int it = 0; it < 2; ++it){
            int cid = it*256 + tid;
            int n = cid >> 2, s = (cid >> 1) & 1, g = cid & 1;
            int k = ko + s*16 + g*8;
            int4 vh = *(const int4*)(wh + (long)n*256 + k);
            int4 vl = *(const int4*)(wl + (long)n*256 + k);
            int slot = ((s*4 + (n >> 5))*64 + g*32 + (n & 31)) * 8;
            *(int4*)&Wh[slot] = vh;
            *(int4*)&Wl[slot] = vl;
        }
        __syncthreads();

        #pragma unroll
        for (int s = 0; s < 2; ++s){
            bf16x8 ah[2], al[2], bh[2], bl[2];
            #pragma unroll
            for (int rm = 0; rm < 2; ++rm){
                int reg = (s*4 + 2*wr + rm)*64 + lane;
                ah[rm] = *(const bf16x8*)&Ah[reg*8];
                al[rm] = *(const bf16x8*)&Al[reg*8];
            }
            #pragma unroll
            for (int cn = 0; cn < 2; ++cn){
                int reg = (s*4 + 2*wc + cn)*64 + lane;
                bh[cn] = *(const bf16x8*)&Wh[reg*8];
                bl[cn] = *(const bf16x8*)&Wl[reg*8];
            }
            #pragma unroll
            for (int rm = 0; rm < 2; ++rm)
                #pragma unroll
                for (int cn = 0; cn < 2; ++cn){
                    acc[rm][cn] = __builtin_amdgcn_mfma_f32_32x32x16_bf16(ah[rm], bh[cn], acc[rm][cn], 0, 0, 0);
                    acc[rm][cn] = __builtin_amdgcn_mfma_f32_32x32x16_bf16(ah[rm], bl[cn], acc[rm][cn], 0, 0, 0);
                    acc[rm][cn] = __builtin_amdgcn_mfma_f32_32x32x16_bf16(al[rm], bh[cn], acc[rm][cn], 0, 0, 0);
                }
        }
        __syncthreads();
    }

    // epilogue: C/D row = (reg&3) + 8*(reg>>2) + 4*(lane>>5), col = lane&31 (m74/m101)
    #pragma unroll
    for (int rm = 0; rm < 2; ++rm)
        #pragma unroll
        for (int cn = 0; cn < 2; ++cn){
            int col = (2*wc + cn)*32 + c32;
            float b = bias[col];
            #pragma unroll
            for (int r = 0; r < 16; ++r){
                int row = row0 + (2*wr + rm)*32 + (r & 3) + 8*(r >> 2) + 4*gg;
                if (row < M){
                    float v = fmaxf(acc[rm][cn][r] + b, 0.f);
                    out[(long)row*128 + col] = v;
                    outh[(long)row*128 + col] = __float2half(v);
                }
            }
        }
}

// ---------------------------------------------------------------- B-row GEMMs via split-bf16 MFMA (16x16x32)
#define AROW 40
// MODE 1: ue = clip([mean1|h][uid] @ wt1^T + b_l1)   N=128
// MODE 3: z0 = relu([ue|lstm] @ wc0^T + bc0)         N=128
template<int MODE>
__global__ __launch_bounds__(256) void gemmB_mfma(const float* __restrict__ a0, const float* __restrict__ a1,
                                                  const int* __restrict__ g,
                                                  const short* __restrict__ wh, const short* __restrict__ wl,
                                                  const float* __restrict__ bias,
                                                  float* __restrict__ out, int ncolsOut, int M){
    __shared__ __align__(16) short Ah[64*AROW];
    __shared__ __align__(16) short Al[64*AROW];
    __shared__ __align__(16) short Wh[128*AROW];
    __shared__ __align__(16) short Wl[128*AROW];

    const int tid  = threadIdx.x;
    const int row0 = blockIdx.x * 64;
    const int wave = tid >> 6, lane = tid & 63;
    const int lm = lane & 15, quad = lane >> 4;

    f32x4 acc[8];
    #pragma unroll
    for (int t = 0; t < 8; ++t) acc[t] = (f32x4){0.f, 0.f, 0.f, 0.f};

    for (int ko = 0; ko < 256; ko += KC){
        #pragma unroll
        for (int it = 0; it < 2; ++it){
            int idx = it*256 + tid;
            int r = idx >> 3, k4 = idx & 7;
            int grow = row0 + r; if (grow >= M) grow = M - 1;
            int k = ko + k4*4;
            float4 v;
            if constexpr (MODE == 1){
                int node = g[grow];
                const float* p = (k < 128) ? a0 + (long)node*128 + k : a1 + (long)node*128 + (k-128);
                v = *(const float4*)p;
            } else {
                const float* p = (k < 128) ? a0 + (long)grow*128 + k : a1 + (long)grow*128 + (k-128);
                v = *(const float4*)p;
            }
            union { short s[4]; int2 p; } ph, pl;
            split_bf16(v.x, ph.s[0], pl.s[0]);
            split_bf16(v.y, ph.s[1], pl.s[1]);
            split_bf16(v.z, ph.s[2], pl.s[2]);
            split_bf16(v.w, ph.s[3], pl.s[3]);
            *(int2*)&Ah[r*AROW + k4*4] = ph.p;
            *(int2*)&Al[r*AROW + k4*4] = pl.p;
        }
        #pragma unroll
        for (int it = 0; it < 2; ++it){
            int idx = it*256 + tid;
            int n = idx >> 2, q = idx & 3;
            int4 vh = *(const int4*)(wh + (long)n*256 + ko + q*8);
            *(int4*)&Wh[n*AROW + q*8] = vh;
            int4 vlo = *(const int4*)(wl + (long)n*256 + ko + q*8);
            *(int4*)&Wl[n*AROW + q*8] = vlo;
        }
        __syncthreads();

        bf16x8 ah = *(const bf16x8*)&Ah[(wave*16 + lm)*AROW + quad*8];
        bf16x8 al = *(const bf16x8*)&Al[(wave*16 + lm)*AROW + quad*8];
        #pragma unroll
        for (int t = 0; t < 8; ++t){
            bf16x8 bh = *(const bf16x8*)&Wh[(t*16 + lm)*AROW + quad*8];
            bf16x8 bl = *(const bf16x8*)&Wl[(t*16 + lm)*AROW + quad*8];
            acc[t] = __builtin_amdgcn_mfma_f32_16x16x32_bf16(ah, bh, acc[t], 0, 0, 0);
            acc[t] = __builtin_amdgcn_mfma_f32_16x16x32_bf16(ah, bl, acc[t], 0, 0, 0);
            acc[t] = __builtin_amdgcn_mfma_f32_16x16x32_bf16(al, bh, acc[t], 0, 0, 0);
        }
        __syncthreads();
    }

    #pragma unroll
    for (int t = 0; t < 8; ++t){
        int gcol = t*16 + lm;
        float b = bias[gcol];
        #pragma unroll
        for (int r = 0; r < 4; ++r){
            int row = row0 + wave*16 + quad*4 + r;
            if (row >= M) continue;
            float v = acc[t][r] + b;
            if constexpr (MODE == 1) v = clipf(v);
            else                     v = fmaxf(v, 0.f);
            out[(long)row*ncolsOut + gcol] = v;
        }
    }
}

// ---------------------------------------------------------------- gates GEMM (all 384 cols) + fused LSTM
// lstm = clip(sig(o)*tanh(sig(i)*tanh(g))) with gates = [ue|clip(x[uid])] @ wg^T + bsum + onehot
__global__ __launch_bounds__(256) void gemmG_mfma(const float* __restrict__ ue, const float* __restrict__ x,
                                                  const int* __restrict__ uid,
                                                  const short* __restrict__ wh, const short* __restrict__ wl,
                                                  const float* __restrict__ bsum, const float* __restrict__ ohtab,
                                                  const int* __restrict__ roles,
                                                  float* __restrict__ lstm, int M){
    __shared__ __align__(16) short Ah[64*AROW];
    __shared__ __align__(16) short Al[64*AROW];
    __shared__ __align__(16) short Wh[128*AROW];
    __shared__ __align__(16) short Wl[128*AROW];

    const int tid  = threadIdx.x;
    const int row0 = blockIdx.x * 64;
    const int wave = tid >> 6, lane = tid & 63;
    const int lm = lane & 15, quad = lane >> 4;

    f32x4 acc[3][8];
    #pragma unroll
    for (int cg = 0; cg < 3; ++cg)
        #pragma unroll
        for (int t = 0; t < 8; ++t) acc[cg][t] = (f32x4){0.f, 0.f, 0.f, 0.f};

    for (int ko = 0; ko < 256; ko += KC){
        // stage A once per ko
        #pragma unroll
        for (int it = 0; it < 2; ++it){
            int idx = it*256 + tid;
            int r = idx >> 3, k4 = idx & 7;
            int grow = row0 + r; if (grow >= M) grow = M - 1;
            int k = ko + k4*4;
            float4 v;
            if (k < 128) v = *(const float4*)(ue + (long)grow*128 + k);
            else {
                int node = uid[grow];
                v = *(const float4*)(x + (long)node*128 + (k-128));
                v.x = clipf(v.x); v.y = clipf(v.y); v.z = clipf(v.z); v.w = clipf(v.w);
            }
            union { short s[4]; int2 p; } ph, pl;
            split_bf16(v.x, ph.s[0], pl.s[0]);
            split_bf16(v.y, ph.s[1], pl.s[1]);
            split_bf16(v.z, ph.s[2], pl.s[2]);
            split_bf16(v.w, ph.s[3], pl.s[3]);
            *(int2*)&Ah[r*AROW + k4*4] = ph.p;
            *(int2*)&Al[r*AROW + k4*4] = pl.p;
        }
        // 3 col-group passes over W, A staged once
        for (int cg = 0; cg < 3; ++cg){
            #pragma unroll
            for (int it = 0; it < 2; ++it){
                int idx = it*256 + tid;
                int n = idx >> 2, q = idx & 3;
                int4 vh = *(const int4*)(wh + (long)(cg*128 + n)*256 + ko + q*8);
                *(int4*)&Wh[n*AROW + q*8] = vh;
                int4 vlo = *(const int4*)(wl + (long)(cg*128 + n)*256 + ko + q*8);
                *(int4*)&Wl[n*AROW + q*8] = vlo;
            }
            __syncthreads();
            bf16x8 ah = *(const bf16x8*)&Ah[(wave*16 + lm)*AROW + quad*8];
            bf16x8 al = *(const bf16x8*)&Al[(wave*16 + lm)*AROW + quad*8];
            #pragma unroll
            for (int t = 0; t < 8; ++t){
                bf16x8 bh = *(const bf16x8*)&Wh[(t*16 + lm)*AROW + quad*8];
                bf16x8 bl = *(const bf16x8*)&Wl[(t*16 + lm)*AROW + quad*8];
                acc[cg][t] = __builtin_amdgcn_mfma_f32_16x16x32_bf16(ah, bh, acc[cg][t], 0, 0, 0);
                acc[cg][t] = __builtin_amdgcn_mfma_f32_16x16x32_bf16(ah, bl, acc[cg][t], 0, 0, 0);
                acc[cg][t] = __builtin_amdgcn_mfma_f32_16x16x32_bf16(al, bh, acc[cg][t], 0, 0, 0);
            }
            __syncthreads();
        }
    }

    // fused LSTM epilogue: i=cols 0-127, g=128-255, o=256-383 (f-gate dead, c0=0)
    #pragma unroll
    for (int r = 0; r < 4; ++r){
        int row = row0 + wave*16 + quad*4 + r;
        if (row >= M) continue;
        const float* oh = ohtab + roles[row]*384;
        #pragma unroll
        for (int t = 0; t < 8; ++t){
            int j = t*16 + lm;
            float i_ = acc[0][t][r] + bsum[j]       + oh[j];
            float g_ = acc[1][t][r] + bsum[128 + j] + oh[128 + j];
            float o_ = acc[2][t][r] + bsum[256 + j] + oh[256 + j];
            float si = 1.f/(1.f + expf(-i_));
            float c  = si * tanhf(g_);
            float so = 1.f/(1.f + expf(-o_));
            lstm[(long)row*128 + j] = clipf(so * tanhf(c));
        }
    }
}

// ---------------------------------------------------------------- fp32 GEMM (z1 = relu(z0 @ wtc1 + bc1))
struct GemmArgs {
    const float* a0; const float* wt;
    const float* bias;
    float* out; int M;
};

__global__ __launch_bounds__(THREADS) void gemm4_k(GemmArgs A){
    constexpr int BM = 64;
    constexpr int BN = 64;
    constexpr int TN = 4;
    constexpr int CT = BN / TN;          // 16
    constexpr int RT = THREADS / CT;     // 16
    constexpr int TM = BM / RT;          // 4
    constexpr int KTOT = 128;
    constexpr int AST = BM + 4;

    __shared__ __align__(16) float As[KC][AST];
    __shared__ __align__(16) float Ws[KC][BN];

    const int tid  = threadIdx.x;
    const int row0 = blockIdx.x * BM;
    const int c  = tid % CT;
    const int rt = tid / CT;

    float acc[TM][TN];
    #pragma unroll
    for (int i = 0; i < TM; ++i)
        #pragma unroll
        for (int j = 0; j < TN; ++j) acc[i][j] = 0.f;

    for (int ko = 0; ko < KTOT; ko += KC){
        #pragma unroll
        for (int it = 0; it < 2; ++it){
            int idx = it*THREADS + tid;
            int r  = idx >> 3;
            int k4 = idx & 7;
            int grow = row0 + r; if (grow >= A.M) grow = A.M - 1;
            float4 v = *(const float4*)(A.a0 + (long)grow*128 + ko + k4*4);
            As[k4*4+0][r] = v.x;
            As[k4*4+1][r] = v.y;
            As[k4*4+2][r] = v.z;
            As[k4*4+3][r] = v.w;
        }
        #pragma unroll
        for (int it = 0; it < 2; ++it){
            int idx = it*THREADS + tid;
            int kk = idx / (BN/4);
            int c4 = idx % (BN/4);
            float4 v = *(const float4*)&A.wt[(long)(ko+kk)*BN + c4*4];
            *(float4*)&Ws[kk][c4*4] = v;
        }
        __syncthreads();
        #pragma unroll
        for (int kk = 0; kk < KC; ++kk){
            float4 wv = *(const float4*)&Ws[kk][c*4];
            float w[TN] = {wv.x, wv.y, wv.z, wv.w};
            float a[TM];
            float4 av = *(const float4*)&As[kk][rt*TM];
            a[0] = av.x; a[1] = av.y; a[2] = av.z; a[3] = av.w;
            #pragma unroll
            for (int i = 0; i < TM; ++i)
                #pragma unroll
                for (int j = 0; j < TN; ++j) acc[i][j] = fmaf(a[i], w[j], acc[i][j]);
        }
        __syncthreads();
    }

    #pragma unroll
    for (int i = 0; i < TM; ++i){
        int grow = row0 + rt*TM + i;
        if (grow >= A.M) continue;
        #pragma unroll
        for (int j = 0; j < TN; ++j){
            int gcol = c*4 + j;
            A.out[(long)grow*64 + gcol] = fmaxf(acc[i][j] + A.bias[gcol], 0.f);
        }
    }
}

// ---------------------------------------------------------------- final tiny GEMM [B,64]@[64,5]
__global__ __launch_bounds__(256) void out_k(const float* __restrict__ z1, const float* __restrict__ wc2, const float* __restrict__ bc2,
                                             float* __restrict__ out, int B){
    int idx = blockIdx.x*256 + threadIdx.x;
    int b = idx >> 3, r = idx & 7;
    if (b >= B || r >= 5) return;
    const float* zr = z1 + (long)b*64;
    const float* wr = wc2 + r*64;
    float acc = bc2[r];
    #pragma unroll 16
    for (int k = 0; k < 64; ++k) acc = fmaf(zr[k], wr[k], acc);
    out[b*5 + r] = acc;
}

// ----------------------------------------------------------------
extern "C" void kernel_launch(void* const* d_in, const int* in_sizes, int n_in,
                              void* d_out, int out_size, void* d_ws, size_t ws_size,
                              hipStream_t stream){
    const float* x     = (const float*)d_in[0];
    const int*   edge  = (const int*)  d_in[1];
    const int*   uid   = (const int*)  d_in[2];
    const int*   roles = (const int*)  d_in[3];
    const float* w_l0  = (const float*)d_in[4];
    const float* b_l0  = (const float*)d_in[5];
    const float* w_r0  = (const float*)d_in[6];
    const float* w_l1  = (const float*)d_in[7];
    const float* b_l1  = (const float*)d_in[8];
    const float* w_r1  = (const float*)d_in[9];
    const float* w_ih  = (const float*)d_in[10];
    // d_in[11] = w_hh: dead (h0 = 0)
    const float* b_ih  = (const float*)d_in[12];
    const float* b_hh  = (const float*)d_in[13];
    const float* wc0   = (const float*)d_in[14];
    const float* bc0   = (const float*)d_in[15];
    const float* wc1   = (const float*)d_in[16];
    const float* bc1   = (const float*)d_in[17];
    const float* wc2   = (const float*)d_in[18];
    const float* bc2   = (const float*)d_in[19];

    const int N = in_sizes[0] / 128;
    const int E = in_sizes[1] / 2;
    const int B = in_sizes[2];
    const int nbuckets = (N + BNODES - 1) >> BSHIFT;

    char* ws = (char*)d_ws;
    size_t off = 0;
    auto alloc = [&](size_t bytes) -> void* {
        void* p = ws + off; off += (bytes + 255) & ~(size_t)255; return p;
    };
    float* arenaA   = (float*)alloc((size_t)N*128*4);   // mean0 -> mean1
    float* arenaB   = (float*)alloc((size_t)N*128*4);   // pairs -> h -> lstm/z0/z1
    float* ue       = (float*)alloc((size_t)B*128*4);
    __half* xh      = (__half*)alloc((size_t)N*128*2);
    __half* hh      = (__half*)alloc((size_t)N*128*2);
    // zero-init region (one memset): flag, ucnt, bcnt
    int*   flag     = (int*)  alloc((size_t)N*4);
    int*   ucnt     = (int*)  alloc(256);
    int*   bcnt     = (int*)  alloc(NB_MAX*4);
    char*  zero_end = ws + off;
    int*   row_start= (int*)  alloc((size_t)(N+1)*4);
    int*   boffs    = (int*)  alloc((size_t)(NB_MAX+1)*4);
    int*   bcur     = (int*)  alloc((size_t)NB_MAX*4);
    int*   col_idx  = (int*)  alloc((size_t)E*4);
    int*   ulist    = (int*)  alloc((size_t)B*4);
    short* wt0h     = (short*)alloc(128*256*2);
    short* wt0l     = (short*)alloc(128*256*2);
    short* wt1h     = (short*)alloc(128*256*2);
    short* wt1l     = (short*)alloc(128*256*2);
    short* wgh      = (short*)alloc(384*256*2);
    short* wgl      = (short*)alloc(384*256*2);
    short* wc0h     = (short*)alloc(128*256*2);
    short* wc0l     = (short*)alloc(128*256*2);
    float* wtc1     = (float*)alloc(128*64*4);
    float* bsum     = (float*)alloc(384*4);
    float* ohtab    = (float*)alloc(5*384*4);

    int2*  pairs = (int2*)arenaB;                // consumed by fill_bucket2 before h is written
    float* mean0 = arenaA;
    float* h     = arenaB;
    float* mean1 = arenaA;
    float* lstm  = arenaB;                       // h consumed by gemmB<1> before gemmG writes
    float* z0    = arenaB + (size_t)B*128;
    float* z1    = arenaB + (size_t)B*128*2;

    hipMemsetAsync(flag, 0, (size_t)(zero_end - (char*)flag), stream);

    const int gEC   = (E + ECHUNK - 1)/ECHUNK;
    const long n8   = (long)N*128/8;
    const int nConv = (int)((n8 + 255)/256);
    const int nPrep = (205184 + 255)/256;
    const int nFlag = (B + 255)/256;

    setup_k<<<nConv + nPrep + nFlag + gEC, 256, 0, stream>>>(
        x, xh, n8, nConv,
        w_l0, w_r0, w_l1, w_r1, wc0, wc1, w_ih, b_ih, b_hh,
        wt0h, wt0l, wt1h, wt1l, wgh, wgl, wc0h, wc0l,
        wtc1, bsum, ohtab, nPrep,
        uid, B, flag, nFlag,
        edge + E, E, nbuckets, bcnt);
    scan_b<<<1, 256, 0, stream>>>(bcnt, nbuckets, E, N, boffs, bcur, row_start);
    bin_edges_priv<<<gEC, 256, 0, stream>>>(edge, edge + E, E, nbuckets, bcur, pairs);
    fill_bucket2<<<nbuckets, 256, 0, stream>>>(pairs, boffs, row_start, col_idx, N);
    compact_flags<<<(N + 255)/256, 256, 0, stream>>>(flag, N, ulist, ucnt);

    // layer 0: mean over all nodes (fp16 gather), then h = relu([mean0|x] @ wt0^T + b_l0); emits h fp16 too
    aggregate_h16<<<(N + 3)/4, 256, 0, stream>>>(xh, row_start, col_idx, mean0, N);
    gemm32_mfma<<<(N + 127)/128, 256, 0, stream>>>(mean0, x, wt0h, wt0l, b_l0, h, hh, N);

    // layer 1: fp16 aggregation for user nodes only, then ue
    aggregate_kh<<<(B + 3)/4, 256, 0, stream>>>(hh, row_start, col_idx, ulist, ucnt, mean1);
    gemmB_mfma<1><<<B/64, 256, 0, stream>>>(mean1, h, uid, wt1h, wt1l, b_l1, ue, 128, B);

    // LSTM gates + activation fused
    gemmG_mfma<<<B/64, 256, 0, stream>>>(ue, x, uid, wgh, wgl, bsum, ohtab, roles, lstm, B);

    // classifier MLP
    gemmB_mfma<3><<<B/64, 256, 0, stream>>>(ue, lstm, nullptr, wc0h, wc0l, bc0, z0, 128, B);
    GemmArgs gz1 { z0, wtc1, bc1, z1, B };
    gemm4_k<<<B/64, THREADS, 0, stream>>>(gz1);
    out_k<<<(B*8 + 255)/256, 256, 0, stream>>>(z1, wc2, bc2, (float*)d_out, B);

    (void)n_in; (void)out_size; (void)ws_size;
}

// Round 11
// 444.490 us; speedup vs baseline: 1.0377x; 1.0377x over previous
//
#include <hip/hip_runtime.h>
#include <hip/hip_fp16.h>
#include <math.h>

#define THREADS 256
#define KC 32
#define BSHIFT 9          // 512 nodes per bucket
#define BNODES (1 << BSHIFT)
#define NB_MAX 256        // max buckets (N<=131072)
#define ECHUNK 4096       // edges per block in binning kernels

__device__ __forceinline__ float clipf(float v){ return fminf(fmaxf(v, -10.f), 10.f); }

typedef __attribute__((ext_vector_type(8))) short bf16x8;
typedef __attribute__((ext_vector_type(4))) float f32x4;
typedef __attribute__((ext_vector_type(16))) float f32x16;

// split fp32 into bf16 hi + bf16 lo (3-term split-GEMM decomposition)
__device__ __forceinline__ void split_bf16(float f, short& hi, short& lo){
    union { float f; unsigned u; } a; a.f = f;
    unsigned r = (a.u + 0x7FFFu + ((a.u >> 16) & 1u)) & 0xFFFF0000u;
    hi = (short)(r >> 16);
    union { unsigned u; float f; } b; b.u = r;
    float rem = f - b.f;
    union { float f; unsigned u; } c; c.f = rem;
    unsigned r2 = c.u + 0x7FFFu + ((c.u >> 16) & 1u);
    lo = (short)(r2 >> 16);
}

// ---------------------------------------------------------------- fused setup:
// [0,nConv)            x -> fp16
// [nConv,+nPrep)       weight prep (split-bf16 + transposes + bias tables)
// [+nFlag)             flag users
// [rest]               bucket histogram
__global__ __launch_bounds__(256) void setup_k(
        const float* __restrict__ x, __half* __restrict__ xh, long n8, int nConv,
        const float* __restrict__ w_l0, const float* __restrict__ w_r0,
        const float* __restrict__ w_l1, const float* __restrict__ w_r1,
        const float* __restrict__ wc0,  const float* __restrict__ wc1,
        const float* __restrict__ w_ih, const float* __restrict__ b_ih, const float* __restrict__ b_hh,
        short* __restrict__ wt0h, short* __restrict__ wt0l,
        short* __restrict__ wt1h, short* __restrict__ wt1l,
        short* __restrict__ wgh,  short* __restrict__ wgl,
        short* __restrict__ wc0h, short* __restrict__ wc0l,
        float* __restrict__ wtc1, float* __restrict__ bsum, float* __restrict__ ohtab, int nPrep,
        const int* __restrict__ uid, int B, int* __restrict__ flag, int nFlag,
        const int* __restrict__ dstv, int E, int nbuckets, int* __restrict__ bcnt){
    __shared__ int hsh[NB_MAX];
    int b = blockIdx.x;
    if (b < nConv){
        long t = (long)b*256 + threadIdx.x;
        if (t >= n8) return;
        long i = t*8;
        float4 a = *(const float4*)(x + i);
        float4 bb = *(const float4*)(x + i + 4);
        union { __half2 h[4]; float4 f; } u;
        u.h[0] = __floats2half2_rn(a.x, a.y);
        u.h[1] = __floats2half2_rn(a.z, a.w);
        u.h[2] = __floats2half2_rn(bb.x, bb.y);
        u.h[3] = __floats2half2_rn(bb.z, bb.w);
        *(float4*)(xh + i) = u.f;
    } else if (b < nConv + nPrep){
        int idx = (b - nConv)*256 + threadIdx.x;
        if (idx < 32768){
            int n = idx >> 8, k = idx & 255;
            float f = (k < 128) ? w_l0[n*128 + k] : w_r0[n*128 + (k - 128)];
            short h, l; split_bf16(f, h, l);
            wt0h[idx] = h; wt0l[idx] = l;
        } else if (idx < 65536){
            int i = idx - 32768;
            int n = i >> 8, k = i & 255;
            float f = (k < 128) ? w_l1[n*128 + k] : w_r1[n*128 + (k - 128)];
            short h, l; split_bf16(f, h, l);
            wt1h[i] = h; wt1l[i] = l;
        } else if (idx < 163840){
            int i = idx - 65536;
            int n = i >> 8, k = i & 255;       // n in [0,384)
            int j = n + ((n >= 128) ? 128 : 0);
            float f = w_ih[j*261 + k];
            short h, l; split_bf16(f, h, l);
            wgh[i] = h; wgl[i] = l;
        } else if (idx < 196608){
            int i = idx - 163840;
            float f = wc0[i];                  // [128][256] already [n][k]
            short h, l; split_bf16(f, h, l);
            wc0h[i] = h; wc0l[i] = l;
        } else if (idx < 204800){
            int i = idx - 196608;
            int j = i >> 7, k = i & 127;
            wtc1[k*64 + j] = wc1[j*128 + k];
        } else if (idx < 205184){
            int jj = idx - 204800;
            int j = jj + ((jj >= 128) ? 128 : 0);
            bsum[jj] = b_ih[j] + b_hh[j];
            for (int r = 0; r < 5; ++r) ohtab[r*384 + jj] = w_ih[j*261 + 256 + r];
        }
    } else if (b < nConv + nPrep + nFlag){
        int i = (b - nConv - nPrep)*256 + threadIdx.x;
        if (i < B) flag[uid[i]] = 1;
    } else {
        int lb = b - nConv - nPrep - nFlag;
        int b0 = lb * ECHUNK;
        int b1 = min(b0 + ECHUNK, E);
        for (int i = threadIdx.x; i < nbuckets; i += 256) hsh[i] = 0;
        __syncthreads();
        for (int i = b0 + threadIdx.x; i < b1; i += 256)
            atomicAdd(&hsh[dstv[i] >> BSHIFT], 1);
        __syncthreads();
        for (int i = threadIdx.x; i < nbuckets; i += 256){
            int c = hsh[i];
            if (c) atomicAdd(&bcnt[i], c);
        }
    }
}

// ---------------------------------------------------------------- CSR build (bucket-first)
__global__ __launch_bounds__(256) void scan_b(const int* __restrict__ bcnt, int nb, int E, int N,
                                              int* __restrict__ boffs, int* __restrict__ bcur, int* __restrict__ row_start){
    __shared__ int sh[256];
    int t = threadIdx.x;
    int v = (t < nb) ? bcnt[t] : 0;
    sh[t] = v; __syncthreads();
    for (int off = 1; off < 256; off <<= 1){
        int u = (t >= off) ? sh[t-off] : 0;
        __syncthreads();
        sh[t] += u;
        __syncthreads();
    }
    int ex = sh[t] - v;
    if (t < nb){ boffs[t] = ex; bcur[t] = ex; }
    if (t == 0){ boffs[nb] = E; row_start[N] = E; }
}

__global__ __launch_bounds__(256) void bin_edges_priv(const int* __restrict__ srcv, const int* __restrict__ dstv, int E,
                                                      int nbuckets, int* __restrict__ bcur, int2* __restrict__ pairs){
    __shared__ int cnt[NB_MAX];
    __shared__ int base[NB_MAX];
    int b0 = blockIdx.x * ECHUNK;
    int b1 = min(b0 + ECHUNK, E);
    for (int i = threadIdx.x; i < nbuckets; i += 256) cnt[i] = 0;
    __syncthreads();
    for (int i = b0 + threadIdx.x; i < b1; i += 256)
        atomicAdd(&cnt[dstv[i] >> BSHIFT], 1);
    __syncthreads();
    for (int i = threadIdx.x; i < nbuckets; i += 256){
        int c = cnt[i];
        base[i] = c ? atomicAdd(&bcur[i], c) : 0;
    }
    __syncthreads();
    for (int i = threadIdx.x; i < nbuckets; i += 256) cnt[i] = 0;
    __syncthreads();
    for (int i = b0 + threadIdx.x; i < b1; i += 256){
        int d = dstv[i];
        int bk = d >> BSHIFT;
        int loc = atomicAdd(&cnt[bk], 1);
        pairs[base[bk] + loc] = make_int2(d, srcv[i]);
    }
}

__global__ __launch_bounds__(256) void fill_bucket2(const int2* __restrict__ pairs, const int* __restrict__ boffs,
                                                    int* __restrict__ row_start, int* __restrict__ col_idx, int N){
    __shared__ int cur[BNODES];
    __shared__ int sh[256];
    int b  = blockIdx.x;
    int n0 = b << BSHIFT;
    int nn = min(BNODES, N - n0);
    int s = boffs[b], e = boffs[b+1];
    int t = threadIdx.x;
    cur[2*t]   = 0;
    cur[2*t+1] = 0;
    __syncthreads();
    for (int i = s + t; i < e; i += 256)
        atomicAdd(&cur[pairs[i].x - n0], 1);
    __syncthreads();
    int c0 = cur[2*t], c1 = cur[2*t+1];
    int s2 = c0 + c1;
    sh[t] = s2; __syncthreads();
    for (int off = 1; off < 256; off <<= 1){
        int u = (t >= off) ? sh[t-off] : 0;
        __syncthreads();
        sh[t] += u;
        __syncthreads();
    }
    int ex = sh[t] - s2;
    __syncthreads();
    cur[2*t]   = s + ex;
    cur[2*t+1] = s + ex + c0;
    __syncthreads();
    for (int i = t; i < nn; i += 256) row_start[n0 + i] = cur[i];
    __syncthreads();
    for (int i = s + t; i < e; i += 256){
        int2 p = pairs[i];
        int loc = atomicAdd(&cur[p.x - n0], 1);
        col_idx[loc] = p.y;
    }
}

__global__ __launch_bounds__(256) void compact_flags(const int* __restrict__ flag, int N, int* __restrict__ list, int* __restrict__ cnt){
    int i = blockIdx.x*256 + threadIdx.x;
    if (i < N && flag[i]){ int p = atomicAdd(cnt, 1); list[p] = i; }
}

// ---------------------------------------------------------------- fp16 mean aggregation (fp32 accum)
__device__ __forceinline__ void accumh(float4& a0, float4& a1, float4 v){
    const __half2* h = (const __half2*)&v;
    float2 f0 = __half22float2(h[0]);
    float2 f1 = __half22float2(h[1]);
    float2 f2 = __half22float2(h[2]);
    float2 f3 = __half22float2(h[3]);
    a0.x += f0.x; a0.y += f0.y; a0.z += f1.x; a0.w += f1.y;
    a1.x += f2.x; a1.y += f2.y; a1.z += f3.x; a1.w += f3.y;
}

// shared body: wave aggregates node's fp16 row-mean into fp32 out (4 edge-groups x 16 lanes)
__device__ __forceinline__ void agg_body(const __half* __restrict__ feat, const int* __restrict__ row_start,
                                         const int* __restrict__ col_idx, float* __restrict__ outmean,
                                         int node, int lane){
    int g  = lane >> 4;
    int sl = lane & 15;
    int s = row_start[node], e = row_start[node+1];
    const float4* f16 = (const float4*)feat;
    float4 a0 = make_float4(0.f,0.f,0.f,0.f);
    float4 a1 = make_float4(0.f,0.f,0.f,0.f);
    int i = s + g;
    for (; i + 12 < e; i += 16){       // 4 loads in flight
        int s0 = col_idx[i];
        int s1 = col_idx[i+4];
        int s2 = col_idx[i+8];
        int s3 = col_idx[i+12];
        float4 v0 = f16[(long)s0*16 + sl];
        float4 v1 = f16[(long)s1*16 + sl];
        float4 v2 = f16[(long)s2*16 + sl];
        float4 v3 = f16[(long)s3*16 + sl];
        accumh(a0, a1, v0);
        accumh(a0, a1, v1);
        accumh(a0, a1, v2);
        accumh(a0, a1, v3);
    }
    if (i + 4 < e){                    // 2-deep tail
        int s0 = col_idx[i];
        int s1 = col_idx[i+4];
        float4 v0 = f16[(long)s0*16 + sl];
        float4 v1 = f16[(long)s1*16 + sl];
        accumh(a0, a1, v0);
        accumh(a0, a1, v1);
        i += 8;
    }
    if (i < e){                        // final single
        float4 v0 = f16[(long)col_idx[i]*16 + sl];
        accumh(a0, a1, v0);
    }
    a0.x += __shfl_xor(a0.x, 16, 64); a0.x += __shfl_xor(a0.x, 32, 64);
    a0.y += __shfl_xor(a0.y, 16, 64); a0.y += __shfl_xor(a0.y, 32, 64);
    a0.z += __shfl_xor(a0.z, 16, 64); a0.z += __shfl_xor(a0.z, 32, 64);
    a0.w += __shfl_xor(a0.w, 16, 64); a0.w += __shfl_xor(a0.w, 32, 64);
    a1.x += __shfl_xor(a1.x, 16, 64); a1.x += __shfl_xor(a1.x, 32, 64);
    a1.y += __shfl_xor(a1.y, 16, 64); a1.y += __shfl_xor(a1.y, 32, 64);
    a1.z += __shfl_xor(a1.z, 16, 64); a1.z += __shfl_xor(a1.z, 32, 64);
    a1.w += __shfl_xor(a1.w, 16, 64); a1.w += __shfl_xor(a1.w, 32, 64);
    if (g == 0){
        float inv = 1.f / fmaxf((float)(e - s), 1.f);
        a0.x *= inv; a0.y *= inv; a0.z *= inv; a0.w *= inv;
        a1.x *= inv; a1.y *= inv; a1.z *= inv; a1.w *= inv;
        float4* om = (float4*)(outmean + (long)node*128 + sl*8);
        om[0] = a0;
        om[1] = a1;
    }
}

__global__ __launch_bounds__(256) void aggregate_h16(const __half* __restrict__ feat, const int* __restrict__ row_start,
                                                     const int* __restrict__ col_idx,
                                                     float* __restrict__ outmean, int N){
    int wave = (blockIdx.x*256 + threadIdx.x) >> 6;
    if (wave >= N) return;
    agg_body(feat, row_start, col_idx, outmean, wave, threadIdx.x & 63);
}

__global__ __launch_bounds__(256) void aggregate_kh(const __half* __restrict__ feat, const int* __restrict__ row_start,
                                                    const int* __restrict__ col_idx,
                                                    const int* __restrict__ list, const int* __restrict__ cnt,
                                                    float* __restrict__ outmean){
    int wave = (blockIdx.x*256 + threadIdx.x) >> 6;
    if (wave >= *cnt) return;
    agg_body(feat, row_start, col_idx, outmean, list[wave], threadIdx.x & 63);
}

// ---------------------------------------------------------------- layer-0 GEMM via split-bf16 32x32x16 MFMA
// h = relu([mean0|x] @ wt0^T + b_l0); also emits fp16 h for the layer-1 gather.
__global__ __launch_bounds__(256) void gemm32_mfma(const float* __restrict__ mean0, const float* __restrict__ x,
                                                   const short* __restrict__ wh, const short* __restrict__ wl,
                                                   const float* __restrict__ bias, float* __restrict__ out,
                                                   __half* __restrict__ outh, int M){
    __shared__ __align__(16) short Ah[8*64*8];   // 8 regions x 64 lanes x 8 shorts = 8 KB
    __shared__ __align__(16) short Al[8*64*8];
    __shared__ __align__(16) short Wh[8*64*8];
    __shared__ __align__(16) short Wl[8*64*8];

    const int tid  = threadIdx.x;
    const int row0 = blockIdx.x * 128;
    const int wave = tid >> 6, lane = tid & 63;
    const int wr = wave >> 1, wc = wave & 1;
    const int c32 = lane & 31, gg = lane >> 5;

    f32x16 acc[2][2];
    #pragma unroll
    for (int rm = 0; rm < 2; ++rm)
        #pragma unroll
        for (int cn = 0; cn < 2; ++cn)
            #pragma unroll
            for (int r = 0; r < 16; ++r) acc[rm][cn][r] = 0.f;

    for (int ko = 0; ko < 256; ko += KC){
        #pragma unroll
        for (int it = 0; it < 2; ++it){
            int cid = it*256 + tid;
            int row = cid >> 2, s = (cid >> 1) & 1, g = cid & 1;
            int grow = row0 + row; if (grow >= M) grow = M - 1;
            int k = ko + s*16 + g*8;
            const float* p = (k < 128) ? (mean0 + (long)grow*128 + k) : (x + (long)grow*128 + (k - 128));
            float4 va = *(const float4*)p;
            float4 vb = *(const float4*)(p + 4);
            union { short s8[8]; int4 v; } ph, pl;
            split_bf16(va.x, ph.s8[0], pl.s8[0]);
            split_bf16(va.y, ph.s8[1], pl.s8[1]);
            split_bf16(va.z, ph.s8[2], pl.s8[2]);
            split_bf16(va.w, ph.s8[3], pl.s8[3]);
            split_bf16(vb.x, ph.s8[4], pl.s8[4]);
            split_bf16(vb.y, ph.s8[5], pl.s8[5]);
            split_bf16(vb.z, ph.s8[6], pl.s8[6]);
            split_bf16(vb.w, ph.s8[7], pl.s8[7]);
            int slot = ((s*4 + (row >> 5))*64 + g*32 + (row & 31)) * 8;
            *(int4*)&Ah[slot] = ph.v;
            *(int4*)&Al[slot] = pl.v;
        }
        #pragma unroll
        for (int it = 0; it < 2; ++it){
            int cid = it*256 + tid;
            int n = cid >> 2, s = (cid >> 1) & 1, g = cid & 1;
            int k = ko + s*16 + g*8;
            int4 vh = *(const int4*)(wh + (long)n*256 + k);
            int4 vl = *(const int4*)(wl + (long)n*256 + k);
            int slot = ((s*4 + (n >> 5))*64 + g*32 + (n & 31)) * 8;
            *(int4*)&Wh[slot] = vh;
            *(int4*)&Wl[slot] = vl;
        }
        __syncthreads();

        #pragma unroll
        for (int s = 0; s < 2; ++s){
            bf16x8 ah[2], al[2], bh[2], bl[2];
            #pragma unroll
            for (int rm = 0; rm < 2; ++rm){
                int reg = (s*4 + 2*wr + rm)*64 + lane;
                ah[rm] = *(const bf16x8*)&Ah[reg*8];
                al[rm] = *(const bf16x8*)&Al[reg*8];
            }
            #pragma unroll
            for (int cn = 0; cn < 2; ++cn){
                int reg = (s*4 + 2*wc + cn)*64 + lane;
                bh[cn] = *(const bf16x8*)&Wh[reg*8];
                bl[cn] = *(const bf16x8*)&Wl[reg*8];
            }
            #pragma unroll
            for (int rm = 0; rm < 2; ++rm)
                #pragma unroll
                for (int cn = 0; cn < 2; ++cn){
                    acc[rm][cn] = __builtin_amdgcn_mfma_f32_32x32x16_bf16(ah[rm], bh[cn], acc[rm][cn], 0, 0, 0);
                    acc[rm][cn] = __builtin_amdgcn_mfma_f32_32x32x16_bf16(ah[rm], bl[cn], acc[rm][cn], 0, 0, 0);
                    acc[rm][cn] = __builtin_amdgcn_mfma_f32_32x32x16_bf16(al[rm], bh[cn], acc[rm][cn], 0, 0, 0);
                }
        }
        __syncthreads();
    }

    // epilogue: C/D row = (reg&3) + 8*(reg>>2) + 4*(lane>>5), col = lane&31 (m74/m101)
    #pragma unroll
    for (int rm = 0; rm < 2; ++rm)
        #pragma unroll
        for (int cn = 0; cn < 2; ++cn){
            int col = (2*wc + cn)*32 + c32;
            float b = bias[col];
            #pragma unroll
            for (int r = 0; r < 16; ++r){
                int row = row0 + (2*wr + rm)*32 + (r & 3) + 8*(r >> 2) + 4*gg;
                if (row < M){
                    float v = fmaxf(acc[rm][cn][r] + b, 0.f);
                    out[(long)row*128 + col] = v;
                    outh[(long)row*128 + col] = __float2half(v);
                }
            }
        }
}

// ---------------------------------------------------------------- B-row GEMMs via split-bf16 MFMA (16x16x32)
#define AROW 40
// MODE 1: ue    = clip([mean1|h][uid] @ wt1^T + b_l1)              N=128
// MODE 2: gates =      [ue|clip(x[uid])] @ wg^T + bsum + onehot    N=384 (gridDim.y=3)
// MODE 3: z0    = relu([ue|lstm] @ wc0^T + bc0)                    N=128
template<int MODE>
__global__ __launch_bounds__(256) void gemmB_mfma(const float* __restrict__ a0, const float* __restrict__ a1,
                                                  const int* __restrict__ g,
                                                  const short* __restrict__ wh, const short* __restrict__ wl,
                                                  const float* __restrict__ bias, const float* __restrict__ ohtab,
                                                  const int* __restrict__ roles,
                                                  float* __restrict__ out, int ncolsOut, int M){
    __shared__ __align__(16) short Ah[64*AROW];
    __shared__ __align__(16) short Al[64*AROW];
    __shared__ __align__(16) short Wh[128*AROW];
    __shared__ __align__(16) short Wl[128*AROW];

    const int tid  = threadIdx.x;
    const int row0 = blockIdx.x * 64;
    const int col0 = blockIdx.y * 128;
    const int wave = tid >> 6, lane = tid & 63;
    const int lm = lane & 15, quad = lane >> 4;

    f32x4 acc[8];
    #pragma unroll
    for (int t = 0; t < 8; ++t) acc[t] = (f32x4){0.f, 0.f, 0.f, 0.f};

    for (int ko = 0; ko < 256; ko += KC){
        #pragma unroll
        for (int it = 0; it < 2; ++it){
            int idx = it*256 + tid;
            int r = idx >> 3, k4 = idx & 7;
            int grow = row0 + r; if (grow >= M) grow = M - 1;
            int k = ko + k4*4;
            float4 v;
            if constexpr (MODE == 1){
                int node = g[grow];
                const float* p = (k < 128) ? a0 + (long)node*128 + k : a1 + (long)node*128 + (k-128);
                v = *(const float4*)p;
            } else if constexpr (MODE == 2){
                if (k < 128) v = *(const float4*)(a0 + (long)grow*128 + k);
                else {
                    int node = g[grow];
                    v = *(const float4*)(a1 + (long)node*128 + (k-128));
                    v.x = clipf(v.x); v.y = clipf(v.y); v.z = clipf(v.z); v.w = clipf(v.w);
                }
            } else {
                const float* p = (k < 128) ? a0 + (long)grow*128 + k : a1 + (long)grow*128 + (k-128);
                v = *(const float4*)p;
            }
            union { short s[4]; int2 p; } ph, pl;
            split_bf16(v.x, ph.s[0], pl.s[0]);
            split_bf16(v.y, ph.s[1], pl.s[1]);
            split_bf16(v.z, ph.s[2], pl.s[2]);
            split_bf16(v.w, ph.s[3], pl.s[3]);
            *(int2*)&Ah[r*AROW + k4*4] = ph.p;
            *(int2*)&Al[r*AROW + k4*4] = pl.p;
        }
        #pragma unroll
        for (int it = 0; it < 2; ++it){
            int idx = it*256 + tid;
            int n = idx >> 2, q = idx & 3;
            int4 vh = *(const int4*)(wh + (long)(col0 + n)*256 + ko + q*8);
            *(int4*)&Wh[n*AROW + q*8] = vh;
            int4 vlo = *(const int4*)(wl + (long)(col0 + n)*256 + ko + q*8);
            *(int4*)&Wl[n*AROW + q*8] = vlo;
        }
        __syncthreads();

        bf16x8 ah = *(const bf16x8*)&Ah[(wave*16 + lm)*AROW + quad*8];
        bf16x8 al = *(const bf16x8*)&Al[(wave*16 + lm)*AROW + quad*8];
        #pragma unroll
        for (int t = 0; t < 8; ++t){
            bf16x8 bh = *(const bf16x8*)&Wh[(t*16 + lm)*AROW + quad*8];
            bf16x8 bl = *(const bf16x8*)&Wl[(t*16 + lm)*AROW + quad*8];
            acc[t] = __builtin_amdgcn_mfma_f32_16x16x32_bf16(ah, bh, acc[t], 0, 0, 0);
            acc[t] = __builtin_amdgcn_mfma_f32_16x16x32_bf16(ah, bl, acc[t], 0, 0, 0);
            acc[t] = __builtin_amdgcn_mfma_f32_16x16x32_bf16(al, bh, acc[t], 0, 0, 0);
        }
        __syncthreads();
    }

    #pragma unroll
    for (int t = 0; t < 8; ++t){
        int gcol = col0 + t*16 + lm;
        float b = bias[gcol];
        #pragma unroll
        for (int r = 0; r < 4; ++r){
            int row = row0 + wave*16 + quad*4 + r;
            if (row >= M) continue;
            float v = acc[t][r] + b;
            if constexpr (MODE == 1)      v = clipf(v);
            else if constexpr (MODE == 2) v = v + ohtab[roles[row]*384 + gcol];
            else                          v = fmaxf(v, 0.f);
            out[(long)row*ncolsOut + gcol] = v;
        }
    }
}

// ---------------------------------------------------------------- LSTM activation (f-gate dead, c0=0)
__global__ __launch_bounds__(256) void lstm_act(const float* __restrict__ gates, float* __restrict__ lstm, int B){
    int idx = blockIdx.x*256 + threadIdx.x;
    if (idx >= B*128) return;
    int b = idx >> 7, j = idx & 127;
    const float* gr = gates + (long)b*384;
    float i_ = gr[j], g_ = gr[128 + j], o_ = gr[256 + j];
    float si = 1.f/(1.f + expf(-i_));
    float c  = si * tanhf(g_);
    float so = 1.f/(1.f + expf(-o_));
    lstm[idx] = clipf(so * tanhf(c));
}

// ---------------------------------------------------------------- fp32 GEMM (z1 = relu(z0 @ wtc1 + bc1))
struct GemmArgs {
    const float* a0; const float* wt;
    const float* bias;
    float* out; int M;
};

__global__ __launch_bounds__(THREADS) void gemm4_k(GemmArgs A){
    constexpr int BM = 64;
    constexpr int BN = 64;
    constexpr int TN = 4;
    constexpr int CT = BN / TN;          // 16
    constexpr int RT = THREADS / CT;     // 16
    constexpr int TM = BM / RT;          // 4
    constexpr int KTOT = 128;
    constexpr int AST = BM + 4;

    __shared__ __align__(16) float As[KC][AST];
    __shared__ __align__(16) float Ws[KC][BN];

    const int tid  = threadIdx.x;
    const int row0 = blockIdx.x * BM;
    const int c  = tid % CT;
    const int rt = tid / CT;

    float acc[TM][TN];
    #pragma unroll
    for (int i = 0; i < TM; ++i)
        #pragma unroll
        for (int j = 0; j < TN; ++j) acc[i][j] = 0.f;

    for (int ko = 0; ko < KTOT; ko += KC){
        #pragma unroll
        for (int it = 0; it < 2; ++it){
            int idx = it*THREADS + tid;
            int r  = idx >> 3;
            int k4 = idx & 7;
            int grow = row0 + r; if (grow >= A.M) grow = A.M - 1;
            float4 v = *(const float4*)(A.a0 + (long)grow*128 + ko + k4*4);
            As[k4*4+0][r] = v.x;
            As[k4*4+1][r] = v.y;
            As[k4*4+2][r] = v.z;
            As[k4*4+3][r] = v.w;
        }
        #pragma unroll
        for (int it = 0; it < 2; ++it){
            int idx = it*THREADS + tid;
            int kk = idx / (BN/4);
            int c4 = idx % (BN/4);
            float4 v = *(const float4*)&A.wt[(long)(ko+kk)*BN + c4*4];
            *(float4*)&Ws[kk][c4*4] = v;
        }
        __syncthreads();
        #pragma unroll
        for (int kk = 0; kk < KC; ++kk){
            float4 wv = *(const float4*)&Ws[kk][c*4];
            float w[TN] = {wv.x, wv.y, wv.z, wv.w};
            float a[TM];
            float4 av = *(const float4*)&As[kk][rt*TM];
            a[0] = av.x; a[1] = av.y; a[2] = av.z; a[3] = av.w;
            #pragma unroll
            for (int i = 0; i < TM; ++i)
                #pragma unroll
                for (int j = 0; j < TN; ++j) acc[i][j] = fmaf(a[i], w[j], acc[i][j]);
        }
        __syncthreads();
    }

    #pragma unroll
    for (int i = 0; i < TM; ++i){
        int grow = row0 + rt*TM + i;
        if (grow >= A.M) continue;
        #pragma unroll
        for (int j = 0; j < TN; ++j){
            int gcol = c*4 + j;
            A.out[(long)grow*64 + gcol] = fmaxf(acc[i][j] + A.bias[gcol], 0.f);
        }
    }
}

// ---------------------------------------------------------------- final tiny GEMM [B,64]@[64,5]
__global__ __launch_bounds__(256) void out_k(const float* __restrict__ z1, const float* __restrict__ wc2, const float* __restrict__ bc2,
                                             float* __restrict__ out, int B){
    int idx = blockIdx.x*256 + threadIdx.x;
    int b = idx >> 3, r = idx & 7;
    if (b >= B || r >= 5) return;
    const float* zr = z1 + (long)b*64;
    const float* wr = wc2 + r*64;
    float acc = bc2[r];
    #pragma unroll 16
    for (int k = 0; k < 64; ++k) acc = fmaf(zr[k], wr[k], acc);
    out[b*5 + r] = acc;
}

// ----------------------------------------------------------------
extern "C" void kernel_launch(void* const* d_in, const int* in_sizes, int n_in,
                              void* d_out, int out_size, void* d_ws, size_t ws_size,
                              hipStream_t stream){
    const float* x     = (const float*)d_in[0];
    const int*   edge  = (const int*)  d_in[1];
    const int*   uid   = (const int*)  d_in[2];
    const int*   roles = (const int*)  d_in[3];
    const float* w_l0  = (const float*)d_in[4];
    const float* b_l0  = (const float*)d_in[5];
    const float* w_r0  = (const float*)d_in[6];
    const float* w_l1  = (const float*)d_in[7];
    const float* b_l1  = (const float*)d_in[8];
    const float* w_r1  = (const float*)d_in[9];
    const float* w_ih  = (const float*)d_in[10];
    // d_in[11] = w_hh: dead (h0 = 0)
    const float* b_ih  = (const float*)d_in[12];
    const float* b_hh  = (const float*)d_in[13];
    const float* wc0   = (const float*)d_in[14];
    const float* bc0   = (const float*)d_in[15];
    const float* wc1   = (const float*)d_in[16];
    const float* bc1   = (const float*)d_in[17];
    const float* wc2   = (const float*)d_in[18];
    const float* bc2   = (const float*)d_in[19];

    const int N = in_sizes[0] / 128;
    const int E = in_sizes[1] / 2;
    const int B = in_sizes[2];
    const int nbuckets = (N + BNODES - 1) >> BSHIFT;

    char* ws = (char*)d_ws;
    size_t off = 0;
    auto alloc = [&](size_t bytes) -> void* {
        void* p = ws + off; off += (bytes + 255) & ~(size_t)255; return p;
    };
    float* arenaA   = (float*)alloc((size_t)N*128*4);   // mean0 -> mean1 -> gates
    float* arenaB   = (float*)alloc((size_t)N*128*4);   // pairs -> h -> lstm/z0/z1
    float* ue       = (float*)alloc((size_t)B*128*4);
    __half* xh      = (__half*)alloc((size_t)N*128*2);
    __half* hh      = (__half*)alloc((size_t)N*128*2);
    // zero-init region (one memset): flag, ucnt, bcnt
    int*   flag     = (int*)  alloc((size_t)N*4);
    int*   ucnt     = (int*)  alloc(256);
    int*   bcnt     = (int*)  alloc(NB_MAX*4);
    char*  zero_end = ws + off;
    int*   row_start= (int*)  alloc((size_t)(N+1)*4);
    int*   boffs    = (int*)  alloc((size_t)(NB_MAX+1)*4);
    int*   bcur     = (int*)  alloc((size_t)NB_MAX*4);
    int*   col_idx  = (int*)  alloc((size_t)E*4);
    int*   ulist    = (int*)  alloc((size_t)B*4);
    short* wt0h     = (short*)alloc(128*256*2);
    short* wt0l     = (short*)alloc(128*256*2);
    short* wt1h     = (short*)alloc(128*256*2);
    short* wt1l     = (short*)alloc(128*256*2);
    short* wgh      = (short*)alloc(384*256*2);
    short* wgl      = (short*)alloc(384*256*2);
    short* wc0h     = (short*)alloc(128*256*2);
    short* wc0l     = (short*)alloc(128*256*2);
    float* wtc1     = (float*)alloc(128*64*4);
    float* bsum     = (float*)alloc(384*4);
    float* ohtab    = (float*)alloc(5*384*4);

    int2*  pairs = (int2*)arenaB;                // consumed by fill_bucket2 before h is written
    float* mean0 = arenaA;
    float* h     = arenaB;
    float* mean1 = arenaA;
    float* gates = arenaA;                       // mean1 consumed by gemmB<1> before this
    float* lstm  = arenaB;                       // h consumed by gemmB<1> before this
    float* z0    = arenaB + (size_t)B*128;
    float* z1    = arenaB + (size_t)B*128*2;

    hipMemsetAsync(flag, 0, (size_t)(zero_end - (char*)flag), stream);

    const int gEC   = (E + ECHUNK - 1)/ECHUNK;
    const long n8   = (long)N*128/8;
    const int nConv = (int)((n8 + 255)/256);
    const int nPrep = (205184 + 255)/256;
    const int nFlag = (B + 255)/256;

    setup_k<<<nConv + nPrep + nFlag + gEC, 256, 0, stream>>>(
        x, xh, n8, nConv,
        w_l0, w_r0, w_l1, w_r1, wc0, wc1, w_ih, b_ih, b_hh,
        wt0h, wt0l, wt1h, wt1l, wgh, wgl, wc0h, wc0l,
        wtc1, bsum, ohtab, nPrep,
        uid, B, flag, nFlag,
        edge + E, E, nbuckets, bcnt);
    scan_b<<<1, 256, 0, stream>>>(bcnt, nbuckets, E, N, boffs, bcur, row_start);
    bin_edges_priv<<<gEC, 256, 0, stream>>>(edge, edge + E, E, nbuckets, bcur, pairs);
    fill_bucket2<<<nbuckets, 256, 0, stream>>>(pairs, boffs, row_start, col_idx, N);
    compact_flags<<<(N + 255)/256, 256, 0, stream>>>(flag, N, ulist, ucnt);

    // layer 0: mean over all nodes (fp16 gather), then h = relu([mean0|x] @ wt0^T + b_l0); emits h fp16 too
    aggregate_h16<<<(N + 3)/4, 256, 0, stream>>>(xh, row_start, col_idx, mean0, N);
    gemm32_mfma<<<(N + 127)/128, 256, 0, stream>>>(mean0, x, wt0h, wt0l, b_l0, h, hh, N);

    // layer 1: fp16 aggregation for user nodes only, then ue
    aggregate_kh<<<(B + 3)/4, 256, 0, stream>>>(hh, row_start, col_idx, ulist, ucnt, mean1);
    gemmB_mfma<1><<<dim3(B/64, 1), 256, 0, stream>>>(mean1, h, uid, wt1h, wt1l, b_l1, nullptr, nullptr, ue, 128, B);

    // LSTM gates (i,g,o only) + activation
    gemmB_mfma<2><<<dim3(B/64, 3), 256, 0, stream>>>(ue, x, uid, wgh, wgl, bsum, ohtab, roles, gates, 384, B);
    lstm_act<<<(B*128 + 255)/256, 256, 0, stream>>>(gates, lstm, B);

    // classifier MLP
    gemmB_mfma<3><<<dim3(B/64, 1), 256, 0, stream>>>(ue, lstm, nullptr, wc0h, wc0l, bc0, nullptr, nullptr, z0, 128, B);
    GemmArgs gz1 { z0, wtc1, bc1, z1, B };
    gemm4_k<<<B/64, THREADS, 0, stream>>>(gz1);
    out_k<<<(B*8 + 255)/256, 256, 0, stream>>>(z1, wc2, bc2, (float*)d_out, B);

    (void)n_in; (void)out_size; (void)ws_size;
}

// Round 12
// 417.235 us; speedup vs baseline: 1.1054x; 1.0653x over previous
//
#include <hip/hip_runtime.h>
#include <hip/hip_fp16.h>
#include <math.h>

#define THREADS 256
#define KC 32
#define BSHIFT 9          // 512 nodes per bucket
#define BNODES (1 << BSHIFT)
#define NB_MAX 256        // max buckets (N<=131072)
#define ECHUNK 4096       // edges per block in binning kernels

__device__ __forceinline__ float clipf(float v){ return fminf(fmaxf(v, -10.f), 10.f); }

typedef __attribute__((ext_vector_type(8))) short bf16x8;
typedef __attribute__((ext_vector_type(8))) _Float16 f16x8;
typedef __attribute__((ext_vector_type(4))) float f32x4;
typedef __attribute__((ext_vector_type(16))) float f32x16;

// split fp32 into bf16 hi + bf16 lo (3-term split-GEMM decomposition)
__device__ __forceinline__ void split_bf16(float f, short& hi, short& lo){
    union { float f; unsigned u; } a; a.f = f;
    unsigned r = (a.u + 0x7FFFu + ((a.u >> 16) & 1u)) & 0xFFFF0000u;
    hi = (short)(r >> 16);
    union { unsigned u; float f; } b; b.u = r;
    float rem = f - b.f;
    union { float f; unsigned u; } c; c.f = rem;
    unsigned r2 = c.u + 0x7FFFu + ((c.u >> 16) & 1u);
    lo = (short)(r2 >> 16);
}

// ---------------------------------------------------------------- fused setup:
// [0,nConv)            x -> fp16
// [nConv,+nPrep)       weight prep (fp16 wt0 + split-bf16 others + bias tables)
// [+nFlag)             flag users
// [rest]               bucket histogram
__global__ __launch_bounds__(256) void setup_k(
        const float* __restrict__ x, __half* __restrict__ xh, long n8, int nConv,
        const float* __restrict__ w_l0, const float* __restrict__ w_r0,
        const float* __restrict__ w_l1, const float* __restrict__ w_r1,
        const float* __restrict__ wc0,  const float* __restrict__ wc1,
        const float* __restrict__ w_ih, const float* __restrict__ b_ih, const float* __restrict__ b_hh,
        __half* __restrict__ wt0f,
        short* __restrict__ wt1h, short* __restrict__ wt1l,
        short* __restrict__ wgh,  short* __restrict__ wgl,
        short* __restrict__ wc0h, short* __restrict__ wc0l,
        float* __restrict__ wtc1, float* __restrict__ bsum, float* __restrict__ ohtab, int nPrep,
        const int* __restrict__ uid, int B, int* __restrict__ flag, int nFlag,
        const int* __restrict__ dstv, int E, int nbuckets, int* __restrict__ bcnt){
    __shared__ int hsh[NB_MAX];
    int b = blockIdx.x;
    if (b < nConv){
        long t = (long)b*256 + threadIdx.x;
        if (t >= n8) return;
        long i = t*8;
        float4 a = *(const float4*)(x + i);
        float4 bb = *(const float4*)(x + i + 4);
        union { __half2 h[4]; float4 f; } u;
        u.h[0] = __floats2half2_rn(a.x, a.y);
        u.h[1] = __floats2half2_rn(a.z, a.w);
        u.h[2] = __floats2half2_rn(bb.x, bb.y);
        u.h[3] = __floats2half2_rn(bb.z, bb.w);
        *(float4*)(xh + i) = u.f;
    } else if (b < nConv + nPrep){
        int idx = (b - nConv)*256 + threadIdx.x;
        if (idx < 32768){
            int n = idx >> 8, k = idx & 255;
            float f = (k < 128) ? w_l0[n*128 + k] : w_r0[n*128 + (k - 128)];
            wt0f[idx] = __float2half(f);
        } else if (idx < 65536){
            int i = idx - 32768;
            int n = i >> 8, k = i & 255;
            float f = (k < 128) ? w_l1[n*128 + k] : w_r1[n*128 + (k - 128)];
            short h, l; split_bf16(f, h, l);
            wt1h[i] = h; wt1l[i] = l;
        } else if (idx < 163840){
            int i = idx - 65536;
            int n = i >> 8, k = i & 255;       // n in [0,384)
            int j = n + ((n >= 128) ? 128 : 0);
            float f = w_ih[j*261 + k];
            short h, l; split_bf16(f, h, l);
            wgh[i] = h; wgl[i] = l;
        } else if (idx < 196608){
            int i = idx - 163840;
            float f = wc0[i];                  // [128][256] already [n][k]
            short h, l; split_bf16(f, h, l);
            wc0h[i] = h; wc0l[i] = l;
        } else if (idx < 204800){
            int i = idx - 196608;
            int j = i >> 7, k = i & 127;
            wtc1[k*64 + j] = wc1[j*128 + k];
        } else if (idx < 205184){
            int jj = idx - 204800;
            int j = jj + ((jj >= 128) ? 128 : 0);
            bsum[jj] = b_ih[j] + b_hh[j];
            for (int r = 0; r < 5; ++r) ohtab[r*384 + jj] = w_ih[j*261 + 256 + r];
        }
    } else if (b < nConv + nPrep + nFlag){
        int i = (b - nConv - nPrep)*256 + threadIdx.x;
        if (i < B) flag[uid[i]] = 1;
    } else {
        int lb = b - nConv - nPrep - nFlag;
        int b0 = lb * ECHUNK;
        int b1 = min(b0 + ECHUNK, E);
        for (int i = threadIdx.x; i < nbuckets; i += 256) hsh[i] = 0;
        __syncthreads();
        for (int i = b0 + threadIdx.x; i < b1; i += 256)
            atomicAdd(&hsh[dstv[i] >> BSHIFT], 1);
        __syncthreads();
        for (int i = threadIdx.x; i < nbuckets; i += 256){
            int c = hsh[i];
            if (c) atomicAdd(&bcnt[i], c);
        }
    }
}

// ---------------------------------------------------------------- CSR build (bucket-first)
__global__ __launch_bounds__(256) void scan_b(const int* __restrict__ bcnt, int nb, int E, int N,
                                              int* __restrict__ boffs, int* __restrict__ bcur, int* __restrict__ row_start){
    __shared__ int sh[256];
    int t = threadIdx.x;
    int v = (t < nb) ? bcnt[t] : 0;
    sh[t] = v; __syncthreads();
    for (int off = 1; off < 256; off <<= 1){
        int u = (t >= off) ? sh[t-off] : 0;
        __syncthreads();
        sh[t] += u;
        __syncthreads();
    }
    int ex = sh[t] - v;
    if (t < nb){ boffs[t] = ex; bcur[t] = ex; }
    if (t == 0){ boffs[nb] = E; row_start[N] = E; }
}

__global__ __launch_bounds__(256) void bin_edges_priv(const int* __restrict__ srcv, const int* __restrict__ dstv, int E,
                                                      int nbuckets, int* __restrict__ bcur, int2* __restrict__ pairs){
    __shared__ int cnt[NB_MAX];
    __shared__ int base[NB_MAX];
    int b0 = blockIdx.x * ECHUNK;
    int b1 = min(b0 + ECHUNK, E);
    for (int i = threadIdx.x; i < nbuckets; i += 256) cnt[i] = 0;
    __syncthreads();
    for (int i = b0 + threadIdx.x; i < b1; i += 256)
        atomicAdd(&cnt[dstv[i] >> BSHIFT], 1);
    __syncthreads();
    for (int i = threadIdx.x; i < nbuckets; i += 256){
        int c = cnt[i];
        base[i] = c ? atomicAdd(&bcur[i], c) : 0;
    }
    __syncthreads();
    for (int i = threadIdx.x; i < nbuckets; i += 256) cnt[i] = 0;
    __syncthreads();
    for (int i = b0 + threadIdx.x; i < b1; i += 256){
        int d = dstv[i];
        int bk = d >> BSHIFT;
        int loc = atomicAdd(&cnt[bk], 1);
        pairs[base[bk] + loc] = make_int2(d, srcv[i]);
    }
}

__global__ __launch_bounds__(256) void fill_bucket2(const int2* __restrict__ pairs, const int* __restrict__ boffs,
                                                    int* __restrict__ row_start, int* __restrict__ col_idx, int N){
    __shared__ int cur[BNODES];
    __shared__ int sh[256];
    int b  = blockIdx.x;
    int n0 = b << BSHIFT;
    int nn = min(BNODES, N - n0);
    int s = boffs[b], e = boffs[b+1];
    int t = threadIdx.x;
    cur[2*t]   = 0;
    cur[2*t+1] = 0;
    __syncthreads();
    for (int i = s + t; i < e; i += 256)
        atomicAdd(&cur[pairs[i].x - n0], 1);
    __syncthreads();
    int c0 = cur[2*t], c1 = cur[2*t+1];
    int s2 = c0 + c1;
    sh[t] = s2; __syncthreads();
    for (int off = 1; off < 256; off <<= 1){
        int u = (t >= off) ? sh[t-off] : 0;
        __syncthreads();
        sh[t] += u;
        __syncthreads();
    }
    int ex = sh[t] - s2;
    __syncthreads();
    cur[2*t]   = s + ex;
    cur[2*t+1] = s + ex + c0;
    __syncthreads();
    for (int i = t; i < nn; i += 256) row_start[n0 + i] = cur[i];
    __syncthreads();
    for (int i = s + t; i < e; i += 256){
        int2 p = pairs[i];
        int loc = atomicAdd(&cur[p.x - n0], 1);
        col_idx[loc] = p.y;
    }
}

__global__ __launch_bounds__(256) void compact_flags(const int* __restrict__ flag, int N, int* __restrict__ list, int* __restrict__ cnt){
    int i = blockIdx.x*256 + threadIdx.x;
    if (i < N && flag[i]){ int p = atomicAdd(cnt, 1); list[p] = i; }
}

// ---------------------------------------------------------------- fp16 mean aggregation (fp32 accum)
__device__ __forceinline__ void accumh(float4& a0, float4& a1, float4 v){
    const __half2* h = (const __half2*)&v;
    float2 f0 = __half22float2(h[0]);
    float2 f1 = __half22float2(h[1]);
    float2 f2 = __half22float2(h[2]);
    float2 f3 = __half22float2(h[3]);
    a0.x += f0.x; a0.y += f0.y; a0.z += f1.x; a0.w += f1.y;
    a1.x += f2.x; a1.y += f2.y; a1.z += f3.x; a1.w += f3.y;
}

// shared body: wave aggregates node's fp16 row-mean into fp32 out (4 edge-groups x 16 lanes)
__device__ __forceinline__ void agg_body(const __half* __restrict__ feat, const int* __restrict__ row_start,
                                         const int* __restrict__ col_idx, float* __restrict__ outmean,
                                         int node, int lane){
    int g  = lane >> 4;
    int sl = lane & 15;
    int s = row_start[node], e = row_start[node+1];
    const float4* f16 = (const float4*)feat;
    float4 a0 = make_float4(0.f,0.f,0.f,0.f);
    float4 a1 = make_float4(0.f,0.f,0.f,0.f);
    int i = s + g;
    for (; i + 12 < e; i += 16){       // 4 loads in flight
        int s0 = col_idx[i];
        int s1 = col_idx[i+4];
        int s2 = col_idx[i+8];
        int s3 = col_idx[i+12];
        float4 v0 = f16[(long)s0*16 + sl];
        float4 v1 = f16[(long)s1*16 + sl];
        float4 v2 = f16[(long)s2*16 + sl];
        float4 v3 = f16[(long)s3*16 + sl];
        accumh(a0, a1, v0);
        accumh(a0, a1, v1);
        accumh(a0, a1, v2);
        accumh(a0, a1, v3);
    }
    if (i + 4 < e){                    // 2-deep tail
        int s0 = col_idx[i];
        int s1 = col_idx[i+4];
        float4 v0 = f16[(long)s0*16 + sl];
        float4 v1 = f16[(long)s1*16 + sl];
        accumh(a0, a1, v0);
        accumh(a0, a1, v1);
        i += 8;
    }
    if (i < e){                        // final single
        float4 v0 = f16[(long)col_idx[i]*16 + sl];
        accumh(a0, a1, v0);
    }
    a0.x += __shfl_xor(a0.x, 16, 64); a0.x += __shfl_xor(a0.x, 32, 64);
    a0.y += __shfl_xor(a0.y, 16, 64); a0.y += __shfl_xor(a0.y, 32, 64);
    a0.z += __shfl_xor(a0.z, 16, 64); a0.z += __shfl_xor(a0.z, 32, 64);
    a0.w += __shfl_xor(a0.w, 16, 64); a0.w += __shfl_xor(a0.w, 32, 64);
    a1.x += __shfl_xor(a1.x, 16, 64); a1.x += __shfl_xor(a1.x, 32, 64);
    a1.y += __shfl_xor(a1.y, 16, 64); a1.y += __shfl_xor(a1.y, 32, 64);
    a1.z += __shfl_xor(a1.z, 16, 64); a1.z += __shfl_xor(a1.z, 32, 64);
    a1.w += __shfl_xor(a1.w, 16, 64); a1.w += __shfl_xor(a1.w, 32, 64);
    if (g == 0){
        float inv = 1.f / fmaxf((float)(e - s), 1.f);
        a0.x *= inv; a0.y *= inv; a0.z *= inv; a0.w *= inv;
        a1.x *= inv; a1.y *= inv; a1.z *= inv; a1.w *= inv;
        float4* om = (float4*)(outmean + (long)node*128 + sl*8);
        om[0] = a0;
        om[1] = a1;
    }
}

__global__ __launch_bounds__(256) void aggregate_h16(const __half* __restrict__ feat, const int* __restrict__ row_start,
                                                     const int* __restrict__ col_idx,
                                                     float* __restrict__ outmean, int N){
    int wave = (blockIdx.x*256 + threadIdx.x) >> 6;
    if (wave >= N) return;
    agg_body(feat, row_start, col_idx, outmean, wave, threadIdx.x & 63);
}

__global__ __launch_bounds__(256) void aggregate_kh(const __half* __restrict__ feat, const int* __restrict__ row_start,
                                                    const int* __restrict__ col_idx,
                                                    const int* __restrict__ list, const int* __restrict__ cnt,
                                                    float* __restrict__ outmean){
    int wave = (blockIdx.x*256 + threadIdx.x) >> 6;
    if (wave >= *cnt) return;
    agg_body(feat, row_start, col_idx, outmean, list[wave], threadIdx.x & 63);
}

// ---------------------------------------------------------------- layer-0 GEMM via f16 32x32x16 MFMA (single-term)
// h(fp16) = relu([mean0|x] @ wt0^T + b_l0). A k>=128 is xh (already fp16); mean0 rounded to fp16.
// Error budget: one extra 2^-11 source on a path that already carries the xh 2^-11 rounding.
__global__ __launch_bounds__(256) void gemm32_mfma(const float* __restrict__ mean0, const __half* __restrict__ xh,
                                                   const __half* __restrict__ wf,
                                                   const float* __restrict__ bias,
                                                   __half* __restrict__ outh, int M){
    __shared__ __align__(16) _Float16 As[8*64*8];   // 8 regions x 64 lanes x 8 halfs = 8 KB
    __shared__ __align__(16) _Float16 Ws[8*64*8];

    const int tid  = threadIdx.x;
    const int row0 = blockIdx.x * 128;
    const int wave = tid >> 6, lane = tid & 63;
    const int wr = wave >> 1, wc = wave & 1;
    const int c32 = lane & 31, gg = lane >> 5;

    f32x16 acc[2][2];
    #pragma unroll
    for (int rm = 0; rm < 2; ++rm)
        #pragma unroll
        for (int cn = 0; cn < 2; ++cn)
            #pragma unroll
            for (int r = 0; r < 16; ++r) acc[rm][cn][r] = 0.f;

    for (int ko = 0; ko < 256; ko += KC){
        // stage A (128 rows x 32 k)
        #pragma unroll
        for (int it = 0; it < 2; ++it){
            int cid = it*256 + tid;
            int row = cid >> 2, s = (cid >> 1) & 1, g = cid & 1;
            int grow = row0 + row; if (grow >= M) grow = M - 1;
            int k = ko + s*16 + g*8;
            int slot = ((s*4 + (row >> 5))*64 + g*32 + (row & 31)) * 8;
            if (k < 128){
                const float* p = mean0 + (long)grow*128 + k;
                float4 va = *(const float4*)p;
                float4 vb = *(const float4*)(p + 4);
                union { __half2 h[4]; int4 v; } u;
                u.h[0] = __floats2half2_rn(va.x, va.y);
                u.h[1] = __floats2half2_rn(va.z, va.w);
                u.h[2] = __floats2half2_rn(vb.x, vb.y);
                u.h[3] = __floats2half2_rn(vb.z, vb.w);
                *(int4*)&As[slot] = u.v;
            } else {
                int4 v = *(const int4*)(xh + (long)grow*128 + (k - 128));
                *(int4*)&As[slot] = v;
            }
        }
        // stage W (128 cols x 32 k), fp16 weights
        #pragma unroll
        for (int it = 0; it < 2; ++it){
            int cid = it*256 + tid;
            int n = cid >> 2, s = (cid >> 1) & 1, g = cid & 1;
            int k = ko + s*16 + g*8;
            int4 vh = *(const int4*)(wf + (long)n*256 + k);
            int slot = ((s*4 + (n >> 5))*64 + g*32 + (n & 31)) * 8;
            *(int4*)&Ws[slot] = vh;
        }
        __syncthreads();

        #pragma unroll
        for (int s = 0; s < 2; ++s){
            f16x8 ah[2], bh[2];
            #pragma unroll
            for (int rm = 0; rm < 2; ++rm){
                int reg = (s*4 + 2*wr + rm)*64 + lane;
                ah[rm] = *(const f16x8*)&As[reg*8];
            }
            #pragma unroll
            for (int cn = 0; cn < 2; ++cn){
                int reg = (s*4 + 2*wc + cn)*64 + lane;
                bh[cn] = *(const f16x8*)&Ws[reg*8];
            }
            #pragma unroll
            for (int rm = 0; rm < 2; ++rm)
                #pragma unroll
                for (int cn = 0; cn < 2; ++cn)
                    acc[rm][cn] = __builtin_amdgcn_mfma_f32_32x32x16_f16(ah[rm], bh[cn], acc[rm][cn], 0, 0, 0);
        }
        __syncthreads();
    }

    // epilogue: C/D row = (reg&3) + 8*(reg>>2) + 4*(lane>>5), col = lane&31 (m74/m101; dtype-independent)
    #pragma unroll
    for (int rm = 0; rm < 2; ++rm)
        #pragma unroll
        for (int cn = 0; cn < 2; ++cn){
            int col = (2*wc + cn)*32 + c32;
            float b = bias[col];
            #pragma unroll
            for (int r = 0; r < 16; ++r){
                int row = row0 + (2*wr + rm)*32 + (r & 3) + 8*(r >> 2) + 4*gg;
                if (row < M)
                    outh[(long)row*128 + col] = __float2half(fmaxf(acc[rm][cn][r] + b, 0.f));
            }
        }
}

// ---------------------------------------------------------------- B-row GEMMs via split-bf16 MFMA (16x16x32)
#define AROW 40
// MODE 1: ue    = clip([mean1|hh[uid]] @ wt1^T + b_l1)             N=128 (a1h = hh fp16)
// MODE 2: gates =      [ue|clip(x[uid])] @ wg^T + bsum + onehot    N=384 (gridDim.y=3)
// MODE 3: z0    = relu([ue|lstm] @ wc0^T + bc0)                    N=128
template<int MODE>
__global__ __launch_bounds__(256) void gemmB_mfma(const float* __restrict__ a0, const float* __restrict__ a1,
                                                  const __half* __restrict__ a1h,
                                                  const int* __restrict__ g,
                                                  const short* __restrict__ wh, const short* __restrict__ wl,
                                                  const float* __restrict__ bias, const float* __restrict__ ohtab,
                                                  const int* __restrict__ roles,
                                                  float* __restrict__ out, int ncolsOut, int M){
    __shared__ __align__(16) short Ah[64*AROW];
    __shared__ __align__(16) short Al[64*AROW];
    __shared__ __align__(16) short Wh[128*AROW];
    __shared__ __align__(16) short Wl[128*AROW];

    const int tid  = threadIdx.x;
    const int row0 = blockIdx.x * 64;
    const int col0 = blockIdx.y * 128;
    const int wave = tid >> 6, lane = tid & 63;
    const int lm = lane & 15, quad = lane >> 4;

    f32x4 acc[8];
    #pragma unroll
    for (int t = 0; t < 8; ++t) acc[t] = (f32x4){0.f, 0.f, 0.f, 0.f};

    for (int ko = 0; ko < 256; ko += KC){
        #pragma unroll
        for (int it = 0; it < 2; ++it){
            int idx = it*256 + tid;
            int r = idx >> 3, k4 = idx & 7;
            int grow = row0 + r; if (grow >= M) grow = M - 1;
            int k = ko + k4*4;
            float4 v;
            if constexpr (MODE == 1){
                int node = g[grow];
                if (k < 128){
                    v = *(const float4*)(a0 + (long)node*128 + k);
                } else {
                    union { int2 p; __half h[4]; } u;
                    u.p = *(const int2*)(a1h + (long)node*128 + (k-128));
                    v.x = __half2float(u.h[0]); v.y = __half2float(u.h[1]);
                    v.z = __half2float(u.h[2]); v.w = __half2float(u.h[3]);
                }
            } else if constexpr (MODE == 2){
                if (k < 128) v = *(const float4*)(a0 + (long)grow*128 + k);
                else {
                    int node = g[grow];
                    v = *(const float4*)(a1 + (long)node*128 + (k-128));
                    v.x = clipf(v.x); v.y = clipf(v.y); v.z = clipf(v.z); v.w = clipf(v.w);
                }
            } else {
                const float* p = (k < 128) ? a0 + (long)grow*128 + k : a1 + (long)grow*128 + (k-128);
                v = *(const float4*)p;
            }
            union { short s[4]; int2 p; } ph, pl;
            split_bf16(v.x, ph.s[0], pl.s[0]);
            split_bf16(v.y, ph.s[1], pl.s[1]);
            split_bf16(v.z, ph.s[2], pl.s[2]);
            split_bf16(v.w, ph.s[3], pl.s[3]);
            *(int2*)&Ah[r*AROW + k4*4] = ph.p;
            *(int2*)&Al[r*AROW + k4*4] = pl.p;
        }
        #pragma unroll
        for (int it = 0; it < 2; ++it){
            int idx = it*256 + tid;
            int n = idx >> 2, q = idx & 3;
            int4 vh = *(const int4*)(wh + (long)(col0 + n)*256 + ko + q*8);
            *(int4*)&Wh[n*AROW + q*8] = vh;
            int4 vlo = *(const int4*)(wl + (long)(col0 + n)*256 + ko + q*8);
            *(int4*)&Wl[n*AROW + q*8] = vlo;
        }
        __syncthreads();

        bf16x8 ah = *(const bf16x8*)&Ah[(wave*16 + lm)*AROW + quad*8];
        bf16x8 al = *(const bf16x8*)&Al[(wave*16 + lm)*AROW + quad*8];
        #pragma unroll
        for (int t = 0; t < 8; ++t){
            bf16x8 bh = *(const bf16x8*)&Wh[(t*16 + lm)*AROW + quad*8];
            bf16x8 bl = *(const bf16x8*)&Wl[(t*16 + lm)*AROW + quad*8];
            acc[t] = __builtin_amdgcn_mfma_f32_16x16x32_bf16(ah, bh, acc[t], 0, 0, 0);
            acc[t] = __builtin_amdgcn_mfma_f32_16x16x32_bf16(ah, bl, acc[t], 0, 0, 0);
            acc[t] = __builtin_amdgcn_mfma_f32_16x16x32_bf16(al, bh, acc[t], 0, 0, 0);
        }
        __syncthreads();
    }

    #pragma unroll
    for (int t = 0; t < 8; ++t){
        int gcol = col0 + t*16 + lm;
        float b = bias[gcol];
        #pragma unroll
        for (int r = 0; r < 4; ++r){
            int row = row0 + wave*16 + quad*4 + r;
            if (row >= M) continue;
            float v = acc[t][r] + b;
            if constexpr (MODE == 1)      v = clipf(v);
            else if constexpr (MODE == 2) v = v + ohtab[roles[row]*384 + gcol];
            else                          v = fmaxf(v, 0.f);
            out[(long)row*ncolsOut + gcol] = v;
        }
    }
}

// ---------------------------------------------------------------- LSTM activation (f-gate dead, c0=0)
__global__ __launch_bounds__(256) void lstm_act(const float* __restrict__ gates, float* __restrict__ lstm, int B){
    int idx = blockIdx.x*256 + threadIdx.x;
    if (idx >= B*128) return;
    int b = idx >> 7, j = idx & 127;
    const float* gr = gates + (long)b*384;
    float i_ = gr[j], g_ = gr[128 + j], o_ = gr[256 + j];
    float si = 1.f/(1.f + expf(-i_));
    float c  = si * tanhf(g_);
    float so = 1.f/(1.f + expf(-o_));
    lstm[idx] = clipf(so * tanhf(c));
}

// ---------------------------------------------------------------- fp32 GEMM (z1 = relu(z0 @ wtc1 + bc1))
struct GemmArgs {
    const float* a0; const float* wt;
    const float* bias;
    float* out; int M;
};

__global__ __launch_bounds__(THREADS) void gemm4_k(GemmArgs A){
    constexpr int BM = 64;
    constexpr int BN = 64;
    constexpr int TN = 4;
    constexpr int CT = BN / TN;          // 16
    constexpr int RT = THREADS / CT;     // 16
    constexpr int TM = BM / RT;          // 4
    constexpr int KTOT = 128;
    constexpr int AST = BM + 4;

    __shared__ __align__(16) float As[KC][AST];
    __shared__ __align__(16) float Ws[KC][BN];

    const int tid  = threadIdx.x;
    const int row0 = blockIdx.x * BM;
    const int c  = tid % CT;
    const int rt = tid / CT;

    float acc[TM][TN];
    #pragma unroll
    for (int i = 0; i < TM; ++i)
        #pragma unroll
        for (int j = 0; j < TN; ++j) acc[i][j] = 0.f;

    for (int ko = 0; ko < KTOT; ko += KC){
        #pragma unroll
        for (int it = 0; it < 2; ++it){
            int idx = it*THREADS + tid;
            int r  = idx >> 3;
            int k4 = idx & 7;
            int grow = row0 + r; if (grow >= A.M) grow = A.M - 1;
            float4 v = *(const float4*)(A.a0 + (long)grow*128 + ko + k4*4);
            As[k4*4+0][r] = v.x;
            As[k4*4+1][r] = v.y;
            As[k4*4+2][r] = v.z;
            As[k4*4+3][r] = v.w;
        }
        #pragma unroll
        for (int it = 0; it < 2; ++it){
            int idx = it*THREADS + tid;
            int kk = idx / (BN/4);
            int c4 = idx % (BN/4);
            float4 v = *(const float4*)&A.wt[(long)(ko+kk)*BN + c4*4];
            *(float4*)&Ws[kk][c4*4] = v;
        }
        __syncthreads();
        #pragma unroll
        for (int kk = 0; kk < KC; ++kk){
            float4 wv = *(const float4*)&Ws[kk][c*4];
            float w[TN] = {wv.x, wv.y, wv.z, wv.w};
            float a[TM];
            float4 av = *(const float4*)&As[kk][rt*TM];
            a[0] = av.x; a[1] = av.y; a[2] = av.z; a[3] = av.w;
            #pragma unroll
            for (int i = 0; i < TM; ++i)
                #pragma unroll
                for (int j = 0; j < TN; ++j) acc[i][j] = fmaf(a[i], w[j], acc[i][j]);
        }
        __syncthreads();
    }

    #pragma unroll
    for (int i = 0; i < TM; ++i){
        int grow = row0 + rt*TM + i;
        if (grow >= A.M) continue;
        #pragma unroll
        for (int j = 0; j < TN; ++j){
            int gcol = c*4 + j;
            A.out[(long)grow*64 + gcol] = fmaxf(acc[i][j] + A.bias[gcol], 0.f);
        }
    }
}

// ---------------------------------------------------------------- final tiny GEMM [B,64]@[64,5]
__global__ __launch_bounds__(256) void out_k(const float* __restrict__ z1, const float* __restrict__ wc2, const float* __restrict__ bc2,
                                             float* __restrict__ out, int B){
    int idx = blockIdx.x*256 + threadIdx.x;
    int b = idx >> 3, r = idx & 7;
    if (b >= B || r >= 5) return;
    const float* zr = z1 + (long)b*64;
    const float* wr = wc2 + r*64;
    float acc = bc2[r];
    #pragma unroll 16
    for (int k = 0; k < 64; ++k) acc = fmaf(zr[k], wr[k], acc);
    out[b*5 + r] = acc;
}

// ----------------------------------------------------------------
extern "C" void kernel_launch(void* const* d_in, const int* in_sizes, int n_in,
                              void* d_out, int out_size, void* d_ws, size_t ws_size,
                              hipStream_t stream){
    const float* x     = (const float*)d_in[0];
    const int*   edge  = (const int*)  d_in[1];
    const int*   uid   = (const int*)  d_in[2];
    const int*   roles = (const int*)  d_in[3];
    const float* w_l0  = (const float*)d_in[4];
    const float* b_l0  = (const float*)d_in[5];
    const float* w_r0  = (const float*)d_in[6];
    const float* w_l1  = (const float*)d_in[7];
    const float* b_l1  = (const float*)d_in[8];
    const float* w_r1  = (const float*)d_in[9];
    const float* w_ih  = (const float*)d_in[10];
    // d_in[11] = w_hh: dead (h0 = 0)
    const float* b_ih  = (const float*)d_in[12];
    const float* b_hh  = (const float*)d_in[13];
    const float* wc0   = (const float*)d_in[14];
    const float* bc0   = (const float*)d_in[15];
    const float* wc1   = (const float*)d_in[16];
    const float* bc1   = (const float*)d_in[17];
    const float* wc2   = (const float*)d_in[18];
    const float* bc2   = (const float*)d_in[19];

    const int N = in_sizes[0] / 128;
    const int E = in_sizes[1] / 2;
    const int B = in_sizes[2];
    const int nbuckets = (N + BNODES - 1) >> BSHIFT;

    char* ws = (char*)d_ws;
    size_t off = 0;
    auto alloc = [&](size_t bytes) -> void* {
        void* p = ws + off; off += (bytes + 255) & ~(size_t)255; return p;
    };
    float* arenaA   = (float*)alloc((size_t)N*128*4);   // mean0 -> mean1 -> gates
    float* arenaB   = (float*)alloc((size_t)N*128*4);   // pairs -> lstm/z0/z1
    float* ue       = (float*)alloc((size_t)B*128*4);
    __half* xh      = (__half*)alloc((size_t)N*128*2);
    __half* hh      = (__half*)alloc((size_t)N*128*2);
    // zero-init region (one memset): flag, ucnt, bcnt
    int*   flag     = (int*)  alloc((size_t)N*4);
    int*   ucnt     = (int*)  alloc(256);
    int*   bcnt     = (int*)  alloc(NB_MAX*4);
    char*  zero_end = ws + off;
    int*   row_start= (int*)  alloc((size_t)(N+1)*4);
    int*   boffs    = (int*)  alloc((size_t)(NB_MAX+1)*4);
    int*   bcur     = (int*)  alloc((size_t)NB_MAX*4);
    int*   col_idx  = (int*)  alloc((size_t)E*4);
    int*   ulist    = (int*)  alloc((size_t)B*4);
    __half* wt0f    = (__half*)alloc(128*256*2);
    short* wt1h     = (short*)alloc(128*256*2);
    short* wt1l     = (short*)alloc(128*256*2);
    short* wgh      = (short*)alloc(384*256*2);
    short* wgl      = (short*)alloc(384*256*2);
    short* wc0h     = (short*)alloc(128*256*2);
    short* wc0l     = (short*)alloc(128*256*2);
    float* wtc1     = (float*)alloc(128*64*4);
    float* bsum     = (float*)alloc(384*4);
    float* ohtab    = (float*)alloc(5*384*4);

    int2*  pairs = (int2*)arenaB;                // consumed by fill_bucket2 before lstm is written
    float* mean0 = arenaA;
    float* mean1 = arenaA;
    float* gates = arenaA;                       // mean1 consumed by gemmB<1> before this
    float* lstm  = arenaB;
    float* z0    = arenaB + (size_t)B*128;
    float* z1    = arenaB + (size_t)B*128*2;

    hipMemsetAsync(flag, 0, (size_t)(zero_end - (char*)flag), stream);

    const int gEC   = (E + ECHUNK - 1)/ECHUNK;
    const long n8   = (long)N*128/8;
    const int nConv = (int)((n8 + 255)/256);
    const int nPrep = (205184 + 255)/256;
    const int nFlag = (B + 255)/256;

    setup_k<<<nConv + nPrep + nFlag + gEC, 256, 0, stream>>>(
        x, xh, n8, nConv,
        w_l0, w_r0, w_l1, w_r1, wc0, wc1, w_ih, b_ih, b_hh,
        wt0f, wt1h, wt1l, wgh, wgl, wc0h, wc0l,
        wtc1, bsum, ohtab, nPrep,
        uid, B, flag, nFlag,
        edge + E, E, nbuckets, bcnt);
    scan_b<<<1, 256, 0, stream>>>(bcnt, nbuckets, E, N, boffs, bcur, row_start);
    bin_edges_priv<<<gEC, 256, 0, stream>>>(edge, edge + E, E, nbuckets, bcur, pairs);
    fill_bucket2<<<nbuckets, 256, 0, stream>>>(pairs, boffs, row_start, col_idx, N);
    compact_flags<<<(N + 255)/256, 256, 0, stream>>>(flag, N, ulist, ucnt);

    // layer 0: mean over all nodes (fp16 gather), then hh = relu([mean0|x] @ wt0^T + b_l0) via f16 MFMA
    aggregate_h16<<<(N + 3)/4, 256, 0, stream>>>(xh, row_start, col_idx, mean0, N);
    gemm32_mfma<<<(N + 127)/128, 256, 0, stream>>>(mean0, xh, wt0f, b_l0, hh, N);

    // layer 1: fp16 aggregation for user nodes only, then ue
    aggregate_kh<<<(B + 3)/4, 256, 0, stream>>>(hh, row_start, col_idx, ulist, ucnt, mean1);
    gemmB_mfma<1><<<dim3(B/64, 1), 256, 0, stream>>>(mean1, nullptr, hh, uid, wt1h, wt1l, b_l1, nullptr, nullptr, ue, 128, B);

    // LSTM gates (i,g,o only) + activation
    gemmB_mfma<2><<<dim3(B/64, 3), 256, 0, stream>>>(ue, x, nullptr, uid, wgh, wgl, bsum, ohtab, roles, gates, 384, B);
    lstm_act<<<(B*128 + 255)/256, 256, 0, stream>>>(gates, lstm, B);

    // classifier MLP
    gemmB_mfma<3><<<dim3(B/64, 1), 256, 0, stream>>>(ue, lstm, nullptr, nullptr, wc0h, wc0l, bc0, nullptr, nullptr, z0, 128, B);
    GemmArgs gz1 { z0, wtc1, bc1, z1, B };
    gemm4_k<<<B/64, THREADS, 0, stream>>>(gz1);
    out_k<<<(B*8 + 255)/256, 256, 0, stream>>>(z1, wc2, bc2, (float*)d_out, B);

    (void)n_in; (void)out_size; (void)ws_size;
}

// Round 14
// 407.826 us; speedup vs baseline: 1.1309x; 1.0231x over previous
//
#include <hip/hip_runtime.h>
#include <hip/hip_fp16.h>
#include <math.h>

#define THREADS 256
#define KC 32
#define BSHIFT 9          // 512 nodes per bucket
#define BNODES (1 << BSHIFT)
#define NB_MAX 256        // max buckets (N<=131072)
#define ECHUNK 4096       // edges per block in binning kernels

__device__ __forceinline__ float clipf(float v){ return fminf(fmaxf(v, -10.f), 10.f); }

typedef __attribute__((ext_vector_type(8))) short bf16x8;
typedef __attribute__((ext_vector_type(8))) _Float16 f16x8;
typedef __attribute__((ext_vector_type(4))) float f32x4;
typedef __attribute__((ext_vector_type(16))) float f32x16;

// split fp32 into bf16 hi + bf16 lo (3-term split-GEMM decomposition)
__device__ __forceinline__ void split_bf16(float f, short& hi, short& lo){
    union { float f; unsigned u; } a; a.f = f;
    unsigned r = (a.u + 0x7FFFu + ((a.u >> 16) & 1u)) & 0xFFFF0000u;
    hi = (short)(r >> 16);
    union { unsigned u; float f; } b; b.u = r;
    float rem = f - b.f;
    union { float f; unsigned u; } c; c.f = rem;
    unsigned r2 = c.u + 0x7FFFu + ((c.u >> 16) & 1u);
    lo = (short)(r2 >> 16);
}

// ---------------------------------------------------------------- fused setup:
__global__ __launch_bounds__(256) void setup_k(
        const float* __restrict__ x, __half* __restrict__ xh, long n8, int nConv,
        const float* __restrict__ w_l0, const float* __restrict__ w_r0,
        const float* __restrict__ w_l1, const float* __restrict__ w_r1,
        const float* __restrict__ wc0,  const float* __restrict__ wc1,
        const float* __restrict__ w_ih, const float* __restrict__ b_ih, const float* __restrict__ b_hh,
        __half* __restrict__ wt0f,
        short* __restrict__ wt1h, short* __restrict__ wt1l,
        short* __restrict__ wgh,  short* __restrict__ wgl,
        short* __restrict__ wc0h, short* __restrict__ wc0l,
        float* __restrict__ wtc1, float* __restrict__ bsum, float* __restrict__ ohtab, int nPrep,
        const int* __restrict__ uid, int B, int* __restrict__ flag, int nFlag,
        const int* __restrict__ dstv, int E, int nbuckets, int* __restrict__ bcnt){
    __shared__ int hsh[NB_MAX];
    int b = blockIdx.x;
    if (b < nConv){
        long t = (long)b*256 + threadIdx.x;
        if (t >= n8) return;
        long i = t*8;
        float4 a = *(const float4*)(x + i);
        float4 bb = *(const float4*)(x + i + 4);
        union { __half2 h[4]; float4 f; } u;
        u.h[0] = __floats2half2_rn(a.x, a.y);
        u.h[1] = __floats2half2_rn(a.z, a.w);
        u.h[2] = __floats2half2_rn(bb.x, bb.y);
        u.h[3] = __floats2half2_rn(bb.z, bb.w);
        *(float4*)(xh + i) = u.f;
    } else if (b < nConv + nPrep){
        int idx = (b - nConv)*256 + threadIdx.x;
        if (idx < 32768){
            int n = idx >> 8, k = idx & 255;
            float f = (k < 128) ? w_l0[n*128 + k] : w_r0[n*128 + (k - 128)];
            wt0f[idx] = __float2half(f);
        } else if (idx < 65536){
            int i = idx - 32768;
            int n = i >> 8, k = i & 255;
            float f = (k < 128) ? w_l1[n*128 + k] : w_r1[n*128 + (k - 128)];
            short h, l; split_bf16(f, h, l);
            wt1h[i] = h; wt1l[i] = l;
        } else if (idx < 163840){
            int i = idx - 65536;
            int n = i >> 8, k = i & 255;       // n in [0,384)
            int j = n + ((n >= 128) ? 128 : 0);
            float f = w_ih[j*261 + k];
            short h, l; split_bf16(f, h, l);
            wgh[i] = h; wgl[i] = l;
        } else if (idx < 196608){
            int i = idx - 163840;
            float f = wc0[i];                  // [128][256] already [n][k]
            short h, l; split_bf16(f, h, l);
            wc0h[i] = h; wc0l[i] = l;
        } else if (idx < 204800){
            int i = idx - 196608;
            int j = i >> 7, k = i & 127;
            wtc1[k*64 + j] = wc1[j*128 + k];
        } else if (idx < 205184){
            int jj = idx - 204800;
            int j = jj + ((jj >= 128) ? 128 : 0);
            bsum[jj] = b_ih[j] + b_hh[j];
            for (int r = 0; r < 5; ++r) ohtab[r*384 + jj] = w_ih[j*261 + 256 + r];
        }
    } else if (b < nConv + nPrep + nFlag){
        int i = (b - nConv - nPrep)*256 + threadIdx.x;
        if (i < B) flag[uid[i]] = 1;
    } else {
        int lb = b - nConv - nPrep - nFlag;
        int b0 = lb * ECHUNK;
        int b1 = min(b0 + ECHUNK, E);
        for (int i = threadIdx.x; i < nbuckets; i += 256) hsh[i] = 0;
        __syncthreads();
        for (int i = b0 + threadIdx.x; i < b1; i += 256)
            atomicAdd(&hsh[dstv[i] >> BSHIFT], 1);
        __syncthreads();
        for (int i = threadIdx.x; i < nbuckets; i += 256){
            int c = hsh[i];
            if (c) atomicAdd(&bcnt[i], c);
        }
    }
}

// ---------------------------------------------------------------- CSR build (bucket-first)
__global__ __launch_bounds__(256) void scan_b(const int* __restrict__ bcnt, int nb, int E, int N,
                                              int* __restrict__ boffs, int* __restrict__ bcur, int* __restrict__ row_start){
    __shared__ int sh[256];
    int t = threadIdx.x;
    int v = (t < nb) ? bcnt[t] : 0;
    sh[t] = v; __syncthreads();
    for (int off = 1; off < 256; off <<= 1){
        int u = (t >= off) ? sh[t-off] : 0;
        __syncthreads();
        sh[t] += u;
        __syncthreads();
    }
    int ex = sh[t] - v;
    if (t < nb){ boffs[t] = ex; bcur[t] = ex; }
    if (t == 0){ boffs[nb] = E; row_start[N] = E; }
}

__global__ __launch_bounds__(256) void bin_edges_priv(const int* __restrict__ srcv, const int* __restrict__ dstv, int E,
                                                      int nbuckets, int* __restrict__ bcur, int2* __restrict__ pairs){
    __shared__ int cnt[NB_MAX];
    __shared__ int base[NB_MAX];
    int b0 = blockIdx.x * ECHUNK;
    int b1 = min(b0 + ECHUNK, E);
    for (int i = threadIdx.x; i < nbuckets; i += 256) cnt[i] = 0;
    __syncthreads();
    for (int i = b0 + threadIdx.x; i < b1; i += 256)
        atomicAdd(&cnt[dstv[i] >> BSHIFT], 1);
    __syncthreads();
    for (int i = threadIdx.x; i < nbuckets; i += 256){
        int c = cnt[i];
        base[i] = c ? atomicAdd(&bcur[i], c) : 0;
    }
    __syncthreads();
    for (int i = threadIdx.x; i < nbuckets; i += 256) cnt[i] = 0;
    __syncthreads();
    for (int i = b0 + threadIdx.x; i < b1; i += 256){
        int d = dstv[i];
        int bk = d >> BSHIFT;
        int loc = atomicAdd(&cnt[bk], 1);
        pairs[base[bk] + loc] = make_int2(d, srcv[i]);
    }
}

__global__ __launch_bounds__(256) void fill_bucket2(const int2* __restrict__ pairs, const int* __restrict__ boffs,
                                                    int* __restrict__ row_start, int* __restrict__ col_idx, int N){
    __shared__ int cur[BNODES];
    __shared__ int sh[256];
    int b  = blockIdx.x;
    int n0 = b << BSHIFT;
    int nn = min(BNODES, N - n0);
    int s = boffs[b], e = boffs[b+1];
    int t = threadIdx.x;
    cur[2*t]   = 0;
    cur[2*t+1] = 0;
    __syncthreads();
    for (int i = s + t; i < e; i += 256)
        atomicAdd(&cur[pairs[i].x - n0], 1);
    __syncthreads();
    int c0 = cur[2*t], c1 = cur[2*t+1];
    int s2 = c0 + c1;
    sh[t] = s2; __syncthreads();
    for (int off = 1; off < 256; off <<= 1){
        int u = (t >= off) ? sh[t-off] : 0;
        __syncthreads();
        sh[t] += u;
        __syncthreads();
    }
    int ex = sh[t] - s2;
    __syncthreads();
    cur[2*t]   = s + ex;
    cur[2*t+1] = s + ex + c0;
    __syncthreads();
    for (int i = t; i < nn; i += 256) row_start[n0 + i] = cur[i];
    __syncthreads();
    for (int i = s + t; i < e; i += 256){
        int2 p = pairs[i];
        int loc = atomicAdd(&cur[p.x - n0], 1);
        col_idx[loc] = p.y;
    }
}

__global__ __launch_bounds__(256) void compact_flags(const int* __restrict__ flag, int N, int* __restrict__ list, int* __restrict__ cnt){
    int i = blockIdx.x*256 + threadIdx.x;
    if (i < N && flag[i]){ int p = atomicAdd(cnt, 1); list[p] = i; }
}

// ---------------------------------------------------------------- fp16 mean aggregation (fp32 accum)
__device__ __forceinline__ void accumh(float4& a0, float4& a1, float4 v){
    const __half2* h = (const __half2*)&v;
    float2 f0 = __half22float2(h[0]);
    float2 f1 = __half22float2(h[1]);
    float2 f2 = __half22float2(h[2]);
    float2 f3 = __half22float2(h[3]);
    a0.x += f0.x; a0.y += f0.y; a0.z += f1.x; a0.w += f1.y;
    a1.x += f2.x; a1.y += f2.y; a1.z += f3.x; a1.w += f3.y;
}

// shared body: wave aggregates node's fp16 row-mean (4 edge-groups x 16 lanes).
// H16OUT: write fp16 (layer-0 mean; numerically identical to downstream fp16 rounding) else fp32.
template<bool H16OUT>
__device__ __forceinline__ void agg_body(const __half* __restrict__ feat, const int* __restrict__ row_start,
                                         const int* __restrict__ col_idx, void* __restrict__ outmean,
                                         int node, int lane){
    int g  = lane >> 4;
    int sl = lane & 15;
    int s = row_start[node], e = row_start[node+1];
    const float4* f16 = (const float4*)feat;
    float4 a0 = make_float4(0.f,0.f,0.f,0.f);
    float4 a1 = make_float4(0.f,0.f,0.f,0.f);
    int i = s + g;
    for (; i + 12 < e; i += 16){       // 4 loads in flight
        int s0 = col_idx[i];
        int s1 = col_idx[i+4];
        int s2 = col_idx[i+8];
        int s3 = col_idx[i+12];
        float4 v0 = f16[(long)s0*16 + sl];
        float4 v1 = f16[(long)s1*16 + sl];
        float4 v2 = f16[(long)s2*16 + sl];
        float4 v3 = f16[(long)s3*16 + sl];
        accumh(a0, a1, v0);
        accumh(a0, a1, v1);
        accumh(a0, a1, v2);
        accumh(a0, a1, v3);
    }
    if (i + 4 < e){                    // 2-deep tail
        int s0 = col_idx[i];
        int s1 = col_idx[i+4];
        float4 v0 = f16[(long)s0*16 + sl];
        float4 v1 = f16[(long)s1*16 + sl];
        accumh(a0, a1, v0);
        accumh(a0, a1, v1);
        i += 8;
    }
    if (i < e){                        // final single
        float4 v0 = f16[(long)col_idx[i]*16 + sl];
        accumh(a0, a1, v0);
    }
    a0.x += __shfl_xor(a0.x, 16, 64); a0.x += __shfl_xor(a0.x, 32, 64);
    a0.y += __shfl_xor(a0.y, 16, 64); a0.y += __shfl_xor(a0.y, 32, 64);
    a0.z += __shfl_xor(a0.z, 16, 64); a0.z += __shfl_xor(a0.z, 32, 64);
    a0.w += __shfl_xor(a0.w, 16, 64); a0.w += __shfl_xor(a0.w, 32, 64);
    a1.x += __shfl_xor(a1.x, 16, 64); a1.x += __shfl_xor(a1.x, 32, 64);
    a1.y += __shfl_xor(a1.y, 16, 64); a1.y += __shfl_xor(a1.y, 32, 64);
    a1.z += __shfl_xor(a1.z, 16, 64); a1.z += __shfl_xor(a1.z, 32, 64);
    a1.w += __shfl_xor(a1.w, 16, 64); a1.w += __shfl_xor(a1.w, 32, 64);
    if (g == 0){
        float inv = 1.f / fmaxf((float)(e - s), 1.f);
        a0.x *= inv; a0.y *= inv; a0.z *= inv; a0.w *= inv;
        a1.x *= inv; a1.y *= inv; a1.z *= inv; a1.w *= inv;
        if constexpr (H16OUT){
            union { __half2 h[4]; int4 v; } u;
            u.h[0] = __floats2half2_rn(a0.x, a0.y);
            u.h[1] = __floats2half2_rn(a0.z, a0.w);
            u.h[2] = __floats2half2_rn(a1.x, a1.y);
            u.h[3] = __floats2half2_rn(a1.z, a1.w);
            *(int4*)((__half*)outmean + (long)node*128 + sl*8) = u.v;
        } else {
            float4* om = (float4*)((float*)outmean + (long)node*128 + sl*8);
            om[0] = a0;
            om[1] = a1;
        }
    }
}

__global__ __launch_bounds__(256) void aggregate_h16(const __half* __restrict__ feat, const int* __restrict__ row_start,
                                                     const int* __restrict__ col_idx,
                                                     __half* __restrict__ outmean, int N){
    int wave = (blockIdx.x*256 + threadIdx.x) >> 6;
    if (wave >= N) return;
    agg_body<true>(feat, row_start, col_idx, outmean, wave, threadIdx.x & 63);
}

__global__ __launch_bounds__(256) void aggregate_kh(const __half* __restrict__ feat, const int* __restrict__ row_start,
                                                    const int* __restrict__ col_idx,
                                                    const int* __restrict__ list, const int* __restrict__ cnt,
                                                    float* __restrict__ outmean){
    int wave = (blockIdx.x*256 + threadIdx.x) >> 6;
    if (wave >= *cnt) return;
    agg_body<false>(feat, row_start, col_idx, outmean, list[wave], threadIdx.x & 63);
}

// ---------------------------------------------------------------- layer-0 GEMM via f16 32x32x16 MFMA (single-term)
// hh = relu([mean0h|xh] @ wt0^T + b_l0); all A inputs already fp16 -> raw int4 staging.
__global__ __launch_bounds__(256) void gemm32_mfma(const __half* __restrict__ mean0h, const __half* __restrict__ xh,
                                                   const __half* __restrict__ wf,
                                                   const float* __restrict__ bias,
                                                   __half* __restrict__ outh, int M){
    __shared__ __align__(16) _Float16 As[8*64*8];   // 8 regions x 64 lanes x 8 halfs = 8 KB
    __shared__ __align__(16) _Float16 Ws[8*64*8];

    const int tid  = threadIdx.x;
    const int row0 = blockIdx.x * 128;
    const int wave = tid >> 6, lane = tid & 63;
    const int wr = wave >> 1, wc = wave & 1;
    const int c32 = lane & 31, gg = lane >> 5;

    f32x16 acc[2][2];
    #pragma unroll
    for (int rm = 0; rm < 2; ++rm)
        #pragma unroll
        for (int cn = 0; cn < 2; ++cn)
            #pragma unroll
            for (int r = 0; r < 16; ++r) acc[rm][cn][r] = 0.f;

    for (int ko = 0; ko < 256; ko += KC){
        // stage A (128 rows x 32 k) — pure int4 copies
        #pragma unroll
        for (int it = 0; it < 2; ++it){
            int cid = it*256 + tid;
            int row = cid >> 2, s = (cid >> 1) & 1, g = cid & 1;
            int grow = row0 + row; if (grow >= M) grow = M - 1;
            int k = ko + s*16 + g*8;
            int slot = ((s*4 + (row >> 5))*64 + g*32 + (row & 31)) * 8;
            const __half* p = (k < 128) ? (mean0h + (long)grow*128 + k) : (xh + (long)grow*128 + (k - 128));
            *(int4*)&As[slot] = *(const int4*)p;
        }
        // stage W (128 cols x 32 k), fp16 weights
        #pragma unroll
        for (int it = 0; it < 2; ++it){
            int cid = it*256 + tid;
            int n = cid >> 2, s = (cid >> 1) & 1, g = cid & 1;
            int k = ko + s*16 + g*8;
            int4 vh = *(const int4*)(wf + (long)n*256 + k);
            int slot = ((s*4 + (n >> 5))*64 + g*32 + (n & 31)) * 8;
            *(int4*)&Ws[slot] = vh;
        }
        __syncthreads();

        #pragma unroll
        for (int s = 0; s < 2; ++s){
            f16x8 ah[2], bh[2];
            #pragma unroll
            for (int rm = 0; rm < 2; ++rm){
                int reg = (s*4 + 2*wr + rm)*64 + lane;
                ah[rm] = *(const f16x8*)&As[reg*8];
            }
            #pragma unroll
            for (int cn = 0; cn < 2; ++cn){
                int reg = (s*4 + 2*wc + cn)*64 + lane;
                bh[cn] = *(const f16x8*)&Ws[reg*8];
            }
            #pragma unroll
            for (int rm = 0; rm < 2; ++rm)
                #pragma unroll
                for (int cn = 0; cn < 2; ++cn)
                    acc[rm][cn] = __builtin_amdgcn_mfma_f32_32x32x16_f16(ah[rm], bh[cn], acc[rm][cn], 0, 0, 0);
        }
        __syncthreads();
    }

    // epilogue: C/D row = (reg&3) + 8*(reg>>2) + 4*(lane>>5), col = lane&31 (m74/m101)
    #pragma unroll
    for (int rm = 0; rm < 2; ++rm)
        #pragma unroll
        for (int cn = 0; cn < 2; ++cn){
            int col = (2*wc + cn)*32 + c32;
            float b = bias[col];
            #pragma unroll
            for (int r = 0; r < 16; ++r){
                int row = row0 + (2*wr + rm)*32 + (r & 3) + 8*(r >> 2) + 4*gg;
                if (row < M)
                    outh[(long)row*128 + col] = __float2half(fmaxf(acc[rm][cn][r] + b, 0.f));
            }
        }
}

// ---------------------------------------------------------------- B-row GEMMs via split-bf16 MFMA (16x16x32)
#define AROW 40
// MODE 1: ue    = clip([mean1|hh[uid]] @ wt1^T + b_l1)             N=128 (a1h = hh fp16)
// MODE 2: gates =      [ue|clip(xh[uid])] @ wg^T + bsum + onehot   N=384 (gridDim.y=3, a1h = xh)
// MODE 3: z0    = relu([ue|lstm] @ wc0^T + bc0)                    N=128
template<int MODE>
__global__ __launch_bounds__(256) void gemmB_mfma(const float* __restrict__ a0, const float* __restrict__ a1,
                                                  const __half* __restrict__ a1h,
                                                  const int* __restrict__ g,
                                                  const short* __restrict__ wh, const short* __restrict__ wl,
                                                  const float* __restrict__ bias, const float* __restrict__ ohtab,
                                                  const int* __restrict__ roles,
                                                  float* __restrict__ out, int ncolsOut, int M){
    __shared__ __align__(16) short Ah[64*AROW];
    __shared__ __align__(16) short Al[64*AROW];
    __shared__ __align__(16) short Wh[128*AROW];
    __shared__ __align__(16) short Wl[128*AROW];

    const int tid  = threadIdx.x;
    const int row0 = blockIdx.x * 64;
    const int col0 = blockIdx.y * 128;
    const int wave = tid >> 6, lane = tid & 63;
    const int lm = lane & 15, quad = lane >> 4;

    f32x4 acc[8];
    #pragma unroll
    for (int t = 0; t < 8; ++t) acc[t] = (f32x4){0.f, 0.f, 0.f, 0.f};

    for (int ko = 0; ko < 256; ko += KC){
        #pragma unroll
        for (int it = 0; it < 2; ++it){
            int idx = it*256 + tid;
            int r = idx >> 3, k4 = idx & 7;
            int grow = row0 + r; if (grow >= M) grow = M - 1;
            int k = ko + k4*4;
            float4 v;
            if constexpr (MODE == 1){
                int node = g[grow];
                if (k < 128){
                    v = *(const float4*)(a0 + (long)node*128 + k);
                } else {
                    union { int2 p; __half h[4]; } u;
                    u.p = *(const int2*)(a1h + (long)node*128 + (k-128));
                    v.x = __half2float(u.h[0]); v.y = __half2float(u.h[1]);
                    v.z = __half2float(u.h[2]); v.w = __half2float(u.h[3]);
                }
            } else if constexpr (MODE == 2){
                if (k < 128) v = *(const float4*)(a0 + (long)grow*128 + k);
                else {
                    int node = g[grow];
                    union { int2 p; __half h[4]; } u;
                    u.p = *(const int2*)(a1h + (long)node*128 + (k-128));
                    v.x = clipf(__half2float(u.h[0])); v.y = clipf(__half2float(u.h[1]));
                    v.z = clipf(__half2float(u.h[2])); v.w = clipf(__half2float(u.h[3]));
                }
            } else {
                const float* p = (k < 128) ? a0 + (long)grow*128 + k : a1 + (long)grow*128 + (k-128);
                v = *(const float4*)p;
            }
            union { short s[4]; int2 p; } ph, pl;
            split_bf16(v.x, ph.s[0], pl.s[0]);
            split_bf16(v.y, ph.s[1], pl.s[1]);
            split_bf16(v.z, ph.s[2], pl.s[2]);
            split_bf16(v.w, ph.s[3], pl.s[3]);
            *(int2*)&Ah[r*AROW + k4*4] = ph.p;
            *(int2*)&Al[r*AROW + k4*4] = pl.p;
        }
        #pragma unroll
        for (int it = 0; it < 2; ++it){
            int idx = it*256 + tid;
            int n = idx >> 2, q = idx & 3;
            int4 vh = *(const int4*)(wh + (long)(col0 + n)*256 + ko + q*8);
            *(int4*)&Wh[n*AROW + q*8] = vh;
            int4 vlo = *(const int4*)(wl + (long)(col0 + n)*256 + ko + q*8);
            *(int4*)&Wl[n*AROW + q*8] = vlo;
        }
        __syncthreads();

        bf16x8 ah = *(const bf16x8*)&Ah[(wave*16 + lm)*AROW + quad*8];
        bf16x8 al = *(const bf16x8*)&Al[(wave*16 + lm)*AROW + quad*8];
        #pragma unroll
        for (int t = 0; t < 8; ++t){
            bf16x8 bh = *(const bf16x8*)&Wh[(t*16 + lm)*AROW + quad*8];
            bf16x8 bl = *(const bf16x8*)&Wl[(t*16 + lm)*AROW + quad*8];
            acc[t] = __builtin_amdgcn_mfma_f32_16x16x32_bf16(ah, bh, acc[t], 0, 0, 0);
            acc[t] = __builtin_amdgcn_mfma_f32_16x16x32_bf16(ah, bl, acc[t], 0, 0, 0);
            acc[t] = __builtin_amdgcn_mfma_f32_16x16x32_bf16(al, bh, acc[t], 0, 0, 0);
        }
        __syncthreads();
    }

    #pragma unroll
    for (int t = 0; t < 8; ++t){
        int gcol = col0 + t*16 + lm;
        float b = bias[gcol];
        #pragma unroll
        for (int r = 0; r < 4; ++r){
            int row = row0 + wave*16 + quad*4 + r;
            if (row >= M) continue;
            float v = acc[t][r] + b;
            if constexpr (MODE == 1)      v = clipf(v);
            else if constexpr (MODE == 2) v = v + ohtab[roles[row]*384 + gcol];
            else                          v = fmaxf(v, 0.f);
            out[(long)row*ncolsOut + gcol] = v;
        }
    }
}

// ---------------------------------------------------------------- LSTM activation (f-gate dead, c0=0)
__global__ __launch_bounds__(256) void lstm_act(const float* __restrict__ gates, float* __restrict__ lstm, int B){
    int idx = blockIdx.x*256 + threadIdx.x;
    if (idx >= B*128) return;
    int b = idx >> 7, j = idx & 127;
    const float* gr = gates + (long)b*384;
    float i_ = gr[j], g_ = gr[128 + j], o_ = gr[256 + j];
    float si = 1.f/(1.f + expf(-i_));
    float c  = si * tanhf(g_);
    float so = 1.f/(1.f + expf(-o_));
    lstm[idx] = clipf(so * tanhf(c));
}

// ---------------------------------------------------------------- fused tail: z1 = relu(z0 @ wtc1 + bc1); out = z1 @ wc2^T + bc2
__global__ __launch_bounds__(THREADS) void tail_k(const float* __restrict__ a0, const float* __restrict__ wt,
                                                  const float* __restrict__ bias,
                                                  const float* __restrict__ wc2, const float* __restrict__ bc2,
                                                  float* __restrict__ out, int M){
    constexpr int BM = 64;
    constexpr int BN = 64;
    constexpr int TN = 4;
    constexpr int CT = BN / TN;          // 16
    constexpr int RT = THREADS / CT;     // 16
    constexpr int TM = BM / RT;          // 4
    constexpr int KTOT = 128;
    constexpr int AST = BM + 4;

    __shared__ __align__(16) float As[KC][AST];
    __shared__ __align__(16) float Ws[KC][BN];
    __shared__ float Zs[BM][BN + 1];     // z1 tile, pad 65 -> conflict-free column reads
    __shared__ float Wc[5][64];

    const int tid  = threadIdx.x;
    const int row0 = blockIdx.x * BM;
    const int c  = tid % CT;
    const int rt = tid / CT;

    for (int i = tid; i < 320; i += THREADS) Wc[i >> 6][i & 63] = wc2[i];   // all 5 rows (bugfix r13)

    float acc[TM][TN];
    #pragma unroll
    for (int i = 0; i < TM; ++i)
        #pragma unroll
        for (int j = 0; j < TN; ++j) acc[i][j] = 0.f;

    for (int ko = 0; ko < KTOT; ko += KC){
        #pragma unroll
        for (int it = 0; it < 2; ++it){
            int idx = it*THREADS + tid;
            int r  = idx >> 3;
            int k4 = idx & 7;
            int grow = row0 + r; if (grow >= M) grow = M - 1;
            float4 v = *(const float4*)(a0 + (long)grow*128 + ko + k4*4);
            As[k4*4+0][r] = v.x;
            As[k4*4+1][r] = v.y;
            As[k4*4+2][r] = v.z;
            As[k4*4+3][r] = v.w;
        }
        #pragma unroll
        for (int it = 0; it < 2; ++it){
            int idx = it*THREADS + tid;
            int kk = idx / (BN/4);
            int c4 = idx % (BN/4);
            float4 v = *(const float4*)&wt[(long)(ko+kk)*BN + c4*4];
            *(float4*)&Ws[kk][c4*4] = v;
        }
        __syncthreads();
        #pragma unroll
        for (int kk = 0; kk < KC; ++kk){
            float4 wv = *(const float4*)&Ws[kk][c*4];
            float w[TN] = {wv.x, wv.y, wv.z, wv.w};
            float a[TM];
            float4 av = *(const float4*)&As[kk][rt*TM];
            a[0] = av.x; a[1] = av.y; a[2] = av.z; a[3] = av.w;
            #pragma unroll
            for (int i = 0; i < TM; ++i)
                #pragma unroll
                for (int j = 0; j < TN; ++j) acc[i][j] = fmaf(a[i], w[j], acc[i][j]);
        }
        __syncthreads();
    }

    // z1 tile -> LDS
    #pragma unroll
    for (int i = 0; i < TM; ++i)
        #pragma unroll
        for (int j = 0; j < TN; ++j)
            Zs[rt*TM + i][c*4 + j] = fmaxf(acc[i][j] + bias[c*4 + j], 0.f);
    __syncthreads();

    // classifier: row = tid&63, j in {tid>>6, tid>>6 + 4} (j<5)
    int row = tid & 63;
    int grow = row0 + row;
    if (grow >= M) return;
    #pragma unroll
    for (int jj = 0; jj < 2; ++jj){
        int j = (tid >> 6) + jj*4;
        if (j >= 5) continue;
        float s = bc2[j];
        #pragma unroll 16
        for (int k = 0; k < 64; ++k) s = fmaf(Zs[row][k], Wc[j][k], s);
        out[(long)grow*5 + j] = s;
    }
}

// ----------------------------------------------------------------
extern "C" void kernel_launch(void* const* d_in, const int* in_sizes, int n_in,
                              void* d_out, int out_size, void* d_ws, size_t ws_size,
                              hipStream_t stream){
    const float* x     = (const float*)d_in[0];
    const int*   edge  = (const int*)  d_in[1];
    const int*   uid   = (const int*)  d_in[2];
    const int*   roles = (const int*)  d_in[3];
    const float* w_l0  = (const float*)d_in[4];
    const float* b_l0  = (const float*)d_in[5];
    const float* w_r0  = (const float*)d_in[6];
    const float* w_l1  = (const float*)d_in[7];
    const float* b_l1  = (const float*)d_in[8];
    const float* w_r1  = (const float*)d_in[9];
    const float* w_ih  = (const float*)d_in[10];
    // d_in[11] = w_hh: dead (h0 = 0)
    const float* b_ih  = (const float*)d_in[12];
    const float* b_hh  = (const float*)d_in[13];
    const float* wc0   = (const float*)d_in[14];
    const float* bc0   = (const float*)d_in[15];
    const float* wc1   = (const float*)d_in[16];
    const float* bc1   = (const float*)d_in[17];
    const float* wc2   = (const float*)d_in[18];
    const float* bc2   = (const float*)d_in[19];

    const int N = in_sizes[0] / 128;
    const int E = in_sizes[1] / 2;
    const int B = in_sizes[2];
    const int nbuckets = (N + BNODES - 1) >> BSHIFT;

    char* ws = (char*)d_ws;
    size_t off = 0;
    auto alloc = [&](size_t bytes) -> void* {
        void* p = ws + off; off += (bytes + 255) & ~(size_t)255; return p;
    };
    float* arenaA   = (float*)alloc((size_t)N*128*4);   // mean0h -> mean1 -> gates
    float* arenaB   = (float*)alloc((size_t)N*128*4);   // pairs -> lstm/z0
    float* ue       = (float*)alloc((size_t)B*128*4);
    __half* xh      = (__half*)alloc((size_t)N*128*2);
    __half* hh      = (__half*)alloc((size_t)N*128*2);
    // zero-init region (one memset): flag, ucnt, bcnt
    int*   flag     = (int*)  alloc((size_t)N*4);
    int*   ucnt     = (int*)  alloc(256);
    int*   bcnt     = (int*)  alloc(NB_MAX*4);
    char*  zero_end = ws + off;
    int*   row_start= (int*)  alloc((size_t)(N+1)*4);
    int*   boffs    = (int*)  alloc((size_t)(NB_MAX+1)*4);
    int*   bcur     = (int*)  alloc((size_t)NB_MAX*4);
    int*   col_idx  = (int*)  alloc((size_t)E*4);
    int*   ulist    = (int*)  alloc((size_t)B*4);
    __half* wt0f    = (__half*)alloc(128*256*2);
    short* wt1h     = (short*)alloc(128*256*2);
    short* wt1l     = (short*)alloc(128*256*2);
    short* wgh      = (short*)alloc(384*256*2);
    short* wgl      = (short*)alloc(384*256*2);
    short* wc0h     = (short*)alloc(128*256*2);
    short* wc0l     = (short*)alloc(128*256*2);
    float* wtc1     = (float*)alloc(128*64*4);
    float* bsum     = (float*)alloc(384*4);
    float* ohtab    = (float*)alloc(5*384*4);

    int2*  pairs = (int2*)arenaB;                // consumed by fill_bucket2 before lstm is written
    __half* mean0h = (__half*)arenaA;
    float* mean1 = arenaA;                       // mean0h consumed by gemm32 before this
    float* gates = arenaA;                       // mean1 consumed by gemmB<1> before this
    float* lstm  = arenaB;
    float* z0    = arenaB + (size_t)B*128;

    hipMemsetAsync(flag, 0, (size_t)(zero_end - (char*)flag), stream);

    const int gEC   = (E + ECHUNK - 1)/ECHUNK;
    const long n8   = (long)N*128/8;
    const int nConv = (int)((n8 + 255)/256);
    const int nPrep = (205184 + 255)/256;
    const int nFlag = (B + 255)/256;

    setup_k<<<nConv + nPrep + nFlag + gEC, 256, 0, stream>>>(
        x, xh, n8, nConv,
        w_l0, w_r0, w_l1, w_r1, wc0, wc1, w_ih, b_ih, b_hh,
        wt0f, wt1h, wt1l, wgh, wgl, wc0h, wc0l,
        wtc1, bsum, ohtab, nPrep,
        uid, B, flag, nFlag,
        edge + E, E, nbuckets, bcnt);
    scan_b<<<1, 256, 0, stream>>>(bcnt, nbuckets, E, N, boffs, bcur, row_start);
    bin_edges_priv<<<gEC, 256, 0, stream>>>(edge, edge + E, E, nbuckets, bcur, pairs);
    fill_bucket2<<<nbuckets, 256, 0, stream>>>(pairs, boffs, row_start, col_idx, N);
    compact_flags<<<(N + 255)/256, 256, 0, stream>>>(flag, N, ulist, ucnt);

    // layer 0: fp16 mean over all nodes, then hh = relu([mean0h|xh] @ wt0^T + b_l0) via f16 MFMA
    aggregate_h16<<<(N + 3)/4, 256, 0, stream>>>(xh, row_start, col_idx, mean0h, N);
    gemm32_mfma<<<(N + 127)/128, 256, 0, stream>>>(mean0h, xh, wt0f, b_l0, hh, N);

    // layer 1: fp16 aggregation for user nodes only, then ue
    aggregate_kh<<<(B + 3)/4, 256, 0, stream>>>(hh, row_start, col_idx, ulist, ucnt, mean1);
    gemmB_mfma<1><<<dim3(B/64, 1), 256, 0, stream>>>(mean1, nullptr, hh, uid, wt1h, wt1l, b_l1, nullptr, nullptr, ue, 128, B);

    // LSTM gates (i,g,o only) + activation
    gemmB_mfma<2><<<dim3(B/64, 3), 256, 0, stream>>>(ue, nullptr, xh, uid, wgh, wgl, bsum, ohtab, roles, gates, 384, B);
    lstm_act<<<(B*128 + 255)/256, 256, 0, stream>>>(gates, lstm, B);

    // classifier MLP (z0 GEMM, then fused z1+out tail)
    gemmB_mfma<3><<<dim3(B/64, 1), 256, 0, stream>>>(ue, lstm, nullptr, nullptr, wc0h, wc0l, bc0, nullptr, nullptr, z0, 128, B);
    tail_k<<<B/64, THREADS, 0, stream>>>(z0, wtc1, bc1, wc2, bc2, (float*)d_out, B);

    (void)n_in; (void)out_size; (void)ws_size;
}